// Round 13
// baseline (309.959 us; speedup 1.0000x reference)
//
#include <hip/hip_runtime.h>
#include <hip/hip_fp16.h>

// ---------------------------------------------------------------------------
// GCN: 2x GraphConv (norm='both') + FC.  fp32 math, fp16 intermediates.
// R2..R8: 5943 -> 325 us (CSR gather, fold FC, MFMA GEMMs, fp16, no atomics).
// R9-R11: reservation partition, lane tuning. 323 us.
// R12/R13: XCD-affinity sliced gather. REGRESSED: per-XCD L2 replication of
//      shared tables is structural (gather FETCH 178 MB == 8 x 22 MB
//      compulsory; rate ~3.1-3.6 TB/s == miss-concurrency cap).
// R14: pad G rows to 128B + merged fine pass. 314.7 us.
// R15: W-frag preconversion; GEMMs LDS-free. 297.9 us.
// R16: 128-node buckets. 290.0 us.
// R17: fused gemm40 into gather epilogue (h1 never hits HBM). 279.1 us.
// R18: gather pre-splits bf16 into LDS (KEPT); gemm128 64-row REGRESSED.
// R19: best-of-each recombination. 277.5 us.
// R20: CHUNK 8192 REGRESSED (313) but EXPOSED scatter as latency-bound;
//      direct deg_out atomics correctness-validated.
// R21: 1024-thread scatter: -2.4 us. 275.1 us.
// R22: scatter||gemm co-launch NEUTRAL (gemm starved scatter's waves).
// R23: fine||gemm co-launch WIN. 271.0 us. Weighted gather costs +5 MB fetch.
// R24: deg_out via direct atomics in scatter (R20-validated) -> es_loc path
//      DELETED (scatter writes halve, LDS 12.8->6.4 KB); fine loses src
//      phase; gemm blocks compute sc=rsqrt(deg_out) and write norm_out as
//      byproduct (co-launch kept); gather back to R19 unweighted form
//      (61.6 us / 178 MB best measured). Cursors zero-based via memsetAsync.
// ---------------------------------------------------------------------------

#define CHUNK    4096   // edges per scatter block (391 blocks)
#define NBK      800    // bin array size (>= nbuck=782)
#define SLAB     3072   // per-bucket slab capacity (mean 2046 + ~22 sigma)

typedef __attribute__((ext_vector_type(8))) short bf16x8;
typedef __attribute__((ext_vector_type(4))) float f32x4;

struct __align__(8)  half4 { __half x, y, z, w; };
struct __align__(16) half8 { __half h[8]; };

__device__ __forceinline__ unsigned short f2bf(float f) {
    union { float f; unsigned u; } v; v.f = f;
    unsigned r = v.u + 0x7FFFu + ((v.u >> 16) & 1u);   // RNE
    return (unsigned short)(r >> 16);
}
__device__ __forceinline__ float bf2f(unsigned short h) {
    union { unsigned u; float f; } v; v.u = ((unsigned)h) << 16;
    return v.f;
}

// ---------------------------------------------------------------------------
// setup: W1 -> frag-ordered bf16-split (Wh1/Wl1), W2p = W2@Wfc folded+
// converted (Wh2/Wl2, cols>=40 zero), b2p = b2@Wfc + bfc.
// (cursor/deg init now done by hipMemsetAsync in kernel_launch)
// ---------------------------------------------------------------------------
__global__ void setup_kernel(const float* __restrict__ W1, const float* __restrict__ W2,
                             const float* __restrict__ Wfc,
                             const float* __restrict__ b2, const float* __restrict__ bfc,
                             unsigned short* __restrict__ Wh1, unsigned short* __restrict__ Wl1,
                             unsigned short* __restrict__ Wh2, unsigned short* __restrict__ Wl2,
                             float* __restrict__ b2p) {
    int idx = blockIdx.x * blockDim.x + threadIdx.x;

    if (idx < 16384) {
        // W1[k][nn] -> frag pos for gemm128
        int k = idx >> 7, nn = idx & 127;
        float v = W1[idx];
        int q = k >> 5, j = k & 7, lb = ((k >> 3) & 3) * 16;
        int tcol = nn >> 4;
        int l = lb + (nn & 15);
        int pos = ((tcol * 4 + q) * 64 + l) * 8 + j;
        unsigned short h = f2bf(v);
        Wh1[pos] = h;
        Wl1[pos] = f2bf(v - bf2f(h));
    } else if (idx < 16384 + 6144) {
        // W2p[k][nn] = dot(W2 row k, Wfc col nn) -> frag pos for fused gemm40
        int i2 = idx - 16384;
        int k = i2 / 48, nn = i2 - k * 48;
        float v = 0.f;
        if (nn < 40) {
            const float* w2row = W2 + k * 128;
            #pragma unroll 8
            for (int jj = 0; jj < 128; ++jj) v += w2row[jj] * Wfc[jj * 40 + nn];
        }
        int t = nn >> 4, q = k >> 5, j = k & 7;
        int l = ((k >> 3) & 3) * 16 + (nn & 15);
        int pos = ((t * 4 + q) * 64 + l) * 8 + j;
        unsigned short h = f2bf(v);
        Wh2[pos] = h;
        Wl2[pos] = f2bf(v - bf2f(h));
    } else if (idx < 16384 + 6144 + 40) {
        int c = idx - (16384 + 6144);
        float a = bfc[c];
        #pragma unroll 8
        for (int j = 0; j < 128; ++j) a += b2[j] * Wfc[j * 40 + c];
        b2p[c] = a;
    }
}

// ------------- single-pass dst partition + direct deg_out atomics -----------
// buckets = dst>>7 (128 nodes, 782 buckets). es_loc path DELETED: deg_out
// computed by direct global atomics in pass 1 (R20-validated correctness).
// cur_d is zero-based (memsetAsync); slab base = bin*SLAB + relative offset.
// 1024 threads/block (best measured, R21).
__global__ __launch_bounds__(1024) void scatter_res_kernel(
        const int* __restrict__ src, const int* __restrict__ dst,
        int* __restrict__ cur_d, int* __restrict__ deg_out,
        unsigned int* __restrict__ ppack, int E) {
    __shared__ int hd[NBK], bd[NBK];
    const int tid = threadIdx.x;
    for (int i = tid; i < NBK; i += 1024) hd[i] = 0;
    __syncthreads();
    const int base = blockIdx.x * CHUNK;
    const int end  = min(base + CHUNK, E);
    for (int e = base + tid; e < end; e += 1024) {
        atomicAdd(&hd[((unsigned)dst[e]) >> 7], 1);
        atomicAdd(&deg_out[src[e]], 1);            // direct out-degree histogram
    }
    __syncthreads();
    for (int i = tid; i < NBK; i += 1024) {
        int cd = hd[i];
        bd[i] = cd ? (i * SLAB + atomicAdd(&cur_d[i], cd)) : 0;
        hd[i] = 0;
    }
    __syncthreads();
    for (int e = base + tid; e < end; e += 1024) {
        int d = dst[e], s = src[e];
        unsigned bin_d = ((unsigned)d) >> 7;
        int pos = bd[bin_d] + atomicAdd(&hd[bin_d], 1);
        ppack[pos] = (((unsigned)d & 127u) << 17) | (unsigned)s;
    }
}

// ---------------------------------------------------------------------------
// CO-LAUNCH: fine-dst (even blocks) || scaled gemm128 (odd blocks).
// fine is dst-only now (src phase deleted). gemm computes its own row scale
// from deg_out and writes norm_out as a byproduct (quad-0 lanes).
// ---------------------------------------------------------------------------
__global__ __launch_bounds__(256, 3) void fine_gemm_kernel(
        const unsigned int* __restrict__ ppack, const int* __restrict__ cur_d,
        const int* __restrict__ deg_out,
        int* __restrict__ deg_in, float* __restrict__ norm_in,
        int* __restrict__ row_ptr, int* __restrict__ csr_src,
        float* __restrict__ norm_out, int N_,
        const float* __restrict__ X,
        const unsigned short* __restrict__ Wh, const unsigned short* __restrict__ Wl,
        __half* __restrict__ Y) {
    const int tid = threadIdx.x;

    if ((blockIdx.x & 1) == 0) {
        // ---------------- fine path (bucket b, dst-only) ----------------
        __shared__ int h[128];
        __shared__ int psum[128];
        const int b = blockIdx.x >> 1;
        const int start = b * SLAB;
        const int node  = (b << 7) + tid;

        const int end_d = start + cur_d[b];        // cur_d holds COUNT now
        if (tid < 128) h[tid] = 0;
        __syncthreads();
        for (int i = start + tid; i < end_d; i += 256)
            atomicAdd(&h[ppack[i] >> 17], 1);
        __syncthreads();

        int a = 0;
        if (tid < 128) { a = h[tid]; psum[tid] = a; }
        __syncthreads();
        for (int off = 1; off < 128; off <<= 1) {
            int t = 0;
            if (tid < 128 && tid >= off) t = psum[tid - off];
            __syncthreads();
            if (tid < 128) psum[tid] += t;
            __syncthreads();
        }

        if (tid < 128) {
            int base0 = psum[tid] - a + start;   // slab-local CSR position
            if (node < N_) {
                deg_in[node]  = a;
                row_ptr[node] = base0;
                norm_in[node] = rsqrtf((float)(a < 1 ? 1 : a));
            }
            h[tid] = base0;
        }
        __syncthreads();

        for (int i = start + tid; i < end_d; i += 256) {
            unsigned int pk = ppack[i];
            int pos = atomicAdd(&h[pk >> 17], 1);
            csr_src[pos] = (int)(pk & 0x1FFFFu);
        }
        return;
    }

    // ---------------- gemm path: Y = (X * sc) @ W1, sc from deg_out -------
    const int blk  = blockIdx.x >> 1;
    const int lane = tid & 63;
    const int w    = tid >> 6;
    const int m    = lane & 15;
    const int quad = lane >> 4;
    const int rowBase = blk * 128 + w * 32;
    const int nrows = N_;

    bf16x8 Ah[2][4], Al[2][4];
    #pragma unroll
    for (int rt = 0; rt < 2; ++rt) {
        int r = rowBase + rt * 16 + m;
        float sc = 0.f;
        if (r < nrows) {
            int d = deg_out[r];
            sc = rsqrtf((float)(d < 1 ? 1 : d));
            if (quad == 0) norm_out[r] = sc;       // byproduct for gather
        }
        const float* xr = X + (size_t)(r < nrows ? r : 0) * 128;
        #pragma unroll
        for (int q = 0; q < 4; ++q) {
            int k0 = q * 32 + quad * 8;
            float4 a = *(const float4*)(xr + k0);
            float4 bv = *(const float4*)(xr + k0 + 4);
            float v[8] = {a.x * sc, a.y * sc, a.z * sc, a.w * sc,
                          bv.x * sc, bv.y * sc, bv.z * sc, bv.w * sc};
            bf16x8 hi, lo;
            #pragma unroll
            for (int j = 0; j < 8; ++j) {
                unsigned short h = f2bf(v[j]);
                hi[j] = (short)h;
                lo[j] = (short)f2bf(v[j] - bf2f(h));
            }
            Ah[rt][q] = hi; Al[rt][q] = lo;
        }
    }

    f32x4 acc[2][8];
    #pragma unroll
    for (int rt = 0; rt < 2; ++rt)
        #pragma unroll
        for (int t = 0; t < 8; ++t)
            acc[rt][t] = (f32x4){0.f, 0.f, 0.f, 0.f};

    #pragma unroll
    for (int t = 0; t < 8; ++t) {
        #pragma unroll
        for (int q = 0; q < 4; ++q) {
            const int off = ((t * 4 + q) * 64 + lane) * 8;
            bf16x8 Bh = *(const bf16x8*)(Wh + off);
            bf16x8 Bl = *(const bf16x8*)(Wl + off);
            #pragma unroll
            for (int rt = 0; rt < 2; ++rt) {
                acc[rt][t] = __builtin_amdgcn_mfma_f32_16x16x32_bf16(Ah[rt][q], Bh, acc[rt][t], 0, 0, 0);
                acc[rt][t] = __builtin_amdgcn_mfma_f32_16x16x32_bf16(Ah[rt][q], Bl, acc[rt][t], 0, 0, 0);
                acc[rt][t] = __builtin_amdgcn_mfma_f32_16x16x32_bf16(Al[rt][q], Bh, acc[rt][t], 0, 0, 0);
            }
        }
    }

    #pragma unroll
    for (int rt = 0; rt < 2; ++rt) {
        int r0 = rowBase + rt * 16 + quad * 4;
        #pragma unroll
        for (int reg = 0; reg < 4; ++reg) {
            int r = r0 + reg;
            if (r >= nrows) continue;
            __half* yr = Y + (size_t)r * 128 + m;
            #pragma unroll
            for (int t = 0; t < 8; ++t)
                yr[t * 16] = __float2half(acc[rt][t][reg]);
        }
    }
}

// ---------------------------------------------------------------------------
// FUSED gather + layer-1 GEMM (R19 unweighted form -- best measured).
// Phase 1 (all 256 threads): h1[node] = relu((sum H[src]) * ni + b1), then
//   pre-scaled by norm_out[node] and SPLIT to bf16 hi/lo in LDS.
// Phase 2 (waves 0-2): pure ds_read_b128 A-frags + 12 MFMA -> G[16 x 40].
// h1 never touches global memory.
// ---------------------------------------------------------------------------
__global__ __launch_bounds__(256, 4) void gather_kernel(
        const __half* __restrict__ H, const int* __restrict__ row_ptr,
        const int* __restrict__ deg, const int* __restrict__ csr_src,
        const float* __restrict__ norm_in, const float* __restrict__ b,
        const float* __restrict__ norm_out,
        const unsigned short* __restrict__ Wh2, const unsigned short* __restrict__ Wl2,
        __half* __restrict__ G, int n) {
    __shared__ unsigned short h1h[16][136];   // bf16 hi, stride 136 (2-way alias max)
    __shared__ unsigned short h1l[16][136];   // bf16 lo
    const int tid   = threadIdx.x;
    const int node0 = blockIdx.x * 16;
    const int g     = tid >> 4;              // node-in-block 0..15
    const int node  = node0 + g;
    const int c     = (tid & 15) * 8;        // column group
    const bool active = node < n;

    int start = 0, cnt = 0;
    if (active) { start = row_ptr[node]; cnt = deg[node]; }
    float acc[8] = {0.f, 0.f, 0.f, 0.f, 0.f, 0.f, 0.f, 0.f};

    int j = 0;
    for (; j + 4 <= cnt; j += 4) {
        int s0 = csr_src[start + j];
        int s1 = csr_src[start + j + 1];
        int s2 = csr_src[start + j + 2];
        int s3 = csr_src[start + j + 3];
        half8 v0 = *(const half8*)(H + (long long)s0 * 128 + c);
        half8 v1 = *(const half8*)(H + (long long)s1 * 128 + c);
        half8 v2 = *(const half8*)(H + (long long)s2 * 128 + c);
        half8 v3 = *(const half8*)(H + (long long)s3 * 128 + c);
        #pragma unroll
        for (int k = 0; k < 8; ++k)
            acc[k] += (__half2float(v0.h[k]) + __half2float(v1.h[k]))
                    + (__half2float(v2.h[k]) + __half2float(v3.h[k]));
    }
    for (; j < cnt; ++j) {
        int s0 = csr_src[start + j];
        half8 v0 = *(const half8*)(H + (long long)s0 * 128 + c);
        #pragma unroll
        for (int k = 0; k < 8; ++k) acc[k] += __half2float(v0.h[k]);
    }

    float ni = active ? norm_in[node]  : 0.f;
    float no = active ? norm_out[node] : 0.f;   // layer-1 row scale, pre-applied
    float4 b0  = *(const float4*)(b + c);
    float4 b1v = *(const float4*)(b + c + 4);
    float bb[8] = {b0.x, b0.y, b0.z, b0.w, b1v.x, b1v.y, b1v.z, b1v.w};
    bf16x8 hi, lo;
    #pragma unroll
    for (int k = 0; k < 8; ++k) {
        float hv = fmaxf(acc[k] * ni + bb[k], 0.f) * no;
        unsigned short h = f2bf(hv);
        hi[k] = (short)h;
        lo[k] = (short)f2bf(hv - bf2f(h));
    }
    *(bf16x8*)&h1h[g][c] = hi;
    *(bf16x8*)&h1l[g][c] = lo;
    __syncthreads();

    // phase 2: waves 0..2 each compute one 16-col tile of G (pure LDS+MFMA)
    const int w = tid >> 6;
    if (w < 3) {
        const int lane = tid & 63;
        const int m    = lane & 15;
        const int quad = lane >> 4;

        f32x4 a3 = (f32x4){0.f, 0.f, 0.f, 0.f};
        const int t = w;
        #pragma unroll
        for (int q = 0; q < 4; ++q) {
            const int k0 = q * 32 + quad * 8;
            bf16x8 Ah = *(const bf16x8*)&h1h[m][k0];
            bf16x8 Al = *(const bf16x8*)&h1l[m][k0];
            const int off = ((t * 4 + q) * 64 + lane) * 8;
            bf16x8 Bh = *(const bf16x8*)(Wh2 + off);
            bf16x8 Bl = *(const bf16x8*)(Wl2 + off);
            a3 = __builtin_amdgcn_mfma_f32_16x16x32_bf16(Ah, Bh, a3, 0, 0, 0);
            a3 = __builtin_amdgcn_mfma_f32_16x16x32_bf16(Ah, Bl, a3, 0, 0, 0);
            a3 = __builtin_amdgcn_mfma_f32_16x16x32_bf16(Al, Bh, a3, 0, 0, 0);
        }

        const int col = t * 16 + m;
        if (col < 40) {
            const int r0 = node0 + quad * 4;
            #pragma unroll
            for (int reg = 0; reg < 4; ++reg) {
                int r = r0 + reg;
                if (r < n) G[(size_t)r * 64 + col] = __float2half(a3[reg]);
            }
        }
    }
}

// 40-dim gather (fp16 in, PADDED stride 64; fp32 out): out = (sum G[src])*ni + b2p
// 5 lanes per node, one half8 (16 B) each.
__global__ __launch_bounds__(256) void gather40_kernel(
        const __half* __restrict__ G, const int* __restrict__ row_ptr,
        const int* __restrict__ deg, const int* __restrict__ csr_src,
        const float* __restrict__ norm_in, const float* __restrict__ b2p,
        float* __restrict__ out, int n) {
    const int t = blockIdx.x * 256 + threadIdx.x;
    if (t >= n * 5) return;
    const int node = t / 5;
    const int c    = (t - node * 5) * 8;

    const int start = row_ptr[node];
    const int cnt   = deg[node];
    float acc[8] = {0.f, 0.f, 0.f, 0.f, 0.f, 0.f, 0.f, 0.f};

    int j = 0;
    for (; j + 4 <= cnt; j += 4) {
        int s0 = csr_src[start + j];
        int s1 = csr_src[start + j + 1];
        int s2 = csr_src[start + j + 2];
        int s3 = csr_src[start + j + 3];
        half8 v0 = *(const half8*)(G + (long long)s0 * 64 + c);
        half8 v1 = *(const half8*)(G + (long long)s1 * 64 + c);
        half8 v2 = *(const half8*)(G + (long long)s2 * 64 + c);
        half8 v3 = *(const half8*)(G + (long long)s3 * 64 + c);
        #pragma unroll
        for (int k = 0; k < 8; ++k)
            acc[k] += (__half2float(v0.h[k]) + __half2float(v1.h[k]))
                    + (__half2float(v2.h[k]) + __half2float(v3.h[k]));
    }
    for (; j < cnt; ++j) {
        int s0 = csr_src[start + j];
        half8 v0 = *(const half8*)(G + (long long)s0 * 64 + c);
        #pragma unroll
        for (int k = 0; k < 8; ++k) acc[k] += __half2float(v0.h[k]);
    }

    float ni = norm_in[node];
    float4 o0, o1;
    o0.x = acc[0] * ni + b2p[c + 0];
    o0.y = acc[1] * ni + b2p[c + 1];
    o0.z = acc[2] * ni + b2p[c + 2];
    o0.w = acc[3] * ni + b2p[c + 3];
    o1.x = acc[4] * ni + b2p[c + 4];
    o1.y = acc[5] * ni + b2p[c + 5];
    o1.z = acc[6] * ni + b2p[c + 6];
    o1.w = acc[7] * ni + b2p[c + 7];
    float* op = out + (long long)node * 40 + c;
    *(float4*)(op)     = o0;
    *(float4*)(op + 4) = o1;
}

extern "C" void kernel_launch(void* const* d_in, const int* in_sizes, int n_in,
                              void* d_out, int out_size, void* d_ws, size_t ws_size,
                              hipStream_t stream) {
    const float* x   = (const float*)d_in[0];
    const int*   ei  = (const int*)  d_in[1];
    const float* W1  = (const float*)d_in[2];
    const float* b1  = (const float*)d_in[3];
    const float* W2  = (const float*)d_in[4];
    const float* b2  = (const float*)d_in[5];
    const float* Wfc = (const float*)d_in[6];
    const float* bfc = (const float*)d_in[7];
    float* out = (float*)d_out;

    const int N = in_sizes[0] / 128;
    const int E = in_sizes[1] / 2;
    const int* src = ei;
    const int* dst = ei + E;

    const int nbuck = (N + 127) >> 7;                  // 782 (== gemm grid)
    const int B1 = (E + CHUNK - 1) / CHUNK;            // 391 scatter blocks

    char* p = (char*)d_ws;
    float* norm_out = (float*)p; p += (size_t)N * 4;
    float* norm_in  = (float*)p; p += (size_t)N * 4;
    float* bufA     = (float*)p; p += (size_t)N * 128 * 4;   // h1pre fp16
    float* bufB     = (float*)p; p += (size_t)N * 128 * 4;   // slabs, then G fp16
    int*   deg_in   = (int*)p;   p += (size_t)N * 4;
    int*   row_ptr  = (int*)p;   p += (size_t)N * 4;
    int*   csr_src  = (int*)p;   p += (size_t)NBK * SLAB * 4;   // slab-indexed CSR
    // contiguous zero-init region: [cur_d | deg_out]
    int*   cur_d    = (int*)p;   p += (size_t)1024 * 4;
    int*   deg_out  = (int*)p;   p += (size_t)N * 4;
    float* b2p      = (float*)p; p += (size_t)64 * 4;
    unsigned short* Wh1 = (unsigned short*)p; p += (size_t)16384 * 2;
    unsigned short* Wl1 = (unsigned short*)p; p += (size_t)16384 * 2;
    unsigned short* Wh2 = (unsigned short*)p; p += (size_t)6144 * 2;
    unsigned short* Wl2 = (unsigned short*)p; p += (size_t)6144 * 2;

    // partition slabs alias bufB (consumed by fine before gather writes G)
    unsigned int* ppack = (unsigned int*)bufB;

    __half* h1pre = (__half*)bufA;   // N x 128 fp16 (scaled X@W1)
    __half* G     = (__half*)bufB;   // N x 64 fp16 PADDED (fused-gather output)

    const int T = 256;

    // zero cursors + deg_out in one async memset (no sync; graph-safe)
    hipMemsetAsync(cur_d, 0, (size_t)(1024 + N) * 4, stream);
    // setup: W1/W2p frag conversion + b2p
    setup_kernel<<<(16384 + 6144 + 40 + T - 1) / T, T, 0, stream>>>(
        W1, W2, Wfc, b2, bfc, Wh1, Wl1, Wh2, Wl2, b2p);
    // partition (1024-thread blocks) + direct deg_out histogram
    scatter_res_kernel<<<B1, 1024, 0, stream>>>(src, dst, cur_d, deg_out,
                                                ppack, E);
    // CO-LAUNCH: fine-dst (even) || scaled gemm128 (odd)
    fine_gemm_kernel<<<2 * nbuck, T, 0, stream>>>(
        ppack, cur_d, deg_out, deg_in, norm_in, row_ptr, csr_src,
        norm_out, N, x, Wh1, Wl1, h1pre);
    // fused gather: sum H[s] -> relu -> (h1*no)@W2p -> G   (h1 stays on-chip)
    const int gather_grid = (N + 15) / 16;
    gather_kernel<<<gather_grid, T, 0, stream>>>(h1pre, row_ptr, deg_in, csr_src,
                                                 norm_in, b1, norm_out,
                                                 Wh2, Wl2, G, N);
    // final gather + bias: out = gather(G) * ni + b2p
    gather40_kernel<<<((size_t)N * 5 + T - 1) / T, T, 0, stream>>>(
        G, row_ptr, deg_in, csr_src, norm_in, b2p, out, N);
}

// Round 14
// 270.870 us; speedup vs baseline: 1.1443x; 1.1443x over previous
//
#include <hip/hip_runtime.h>
#include <hip/hip_fp16.h>

// ---------------------------------------------------------------------------
// GCN: 2x GraphConv (norm='both') + FC.  fp32 math, fp16 intermediates.
// R2..R8: 5943 -> 325 us (CSR gather, fold FC, MFMA GEMMs, fp16, no atomics).
// R9-R11: reservation partition, lane tuning. 323 us.
// R12/R13: XCD-affinity sliced gather. REGRESSED: per-XCD L2 replication of
//      shared tables is structural (gather FETCH 178 MB == 8 x 22 MB
//      compulsory; rate ~3.1-3.6 TB/s == miss-concurrency cap).
// R14: pad G rows to 128B + merged fine pass. 314.7 us.
// R15: W-frag preconversion; GEMMs LDS-free. 297.9 us.
// R16: 128-node buckets. 290.0 us.
// R17: fused gemm40 into gather epilogue (h1 never hits HBM). 279.1 us.
// R18: gather pre-splits bf16 into LDS (KEPT); gemm128 64-row REGRESSED.
// R19: best-of-each recombination. 277.5 us.
// R20/R24: direct global deg_out atomics REGRESSED BOTH TIMES (82/78 us
//      scatter even at 54% occupancy): cross-XCD coherence forces random
//      device-scope atomics to the shared level -- 1.6M serialized RMWs.
//      RULE: LDS-binned histograms only; never random global atomics here.
// R21: 1024-thread scatter: -2.4 us. 275.1 us.
// R22: scatter||gemm co-launch NEUTRAL (gemm starved scatter's waves).
// R23: fine||gemm co-launch WIN. 271.0 us (best).
// R25: R23 + scatter edge loads vectorized (int4, 4 edges/thread) and HELD
//      IN REGISTERS across the reservation barrier -- edge stream read once
//      (12.8 -> 6.4 MB), 1/4 VMEM instructions, no pass-3 recompute.
// ---------------------------------------------------------------------------

#define CHUNK    4096   // edges per scatter block (391 blocks)
#define NBK      800    // bin array size (>= nbuck=782)
#define SLAB     3072   // per-bucket slab capacity (mean 2046 + ~22 sigma)

typedef __attribute__((ext_vector_type(8))) short bf16x8;
typedef __attribute__((ext_vector_type(4))) float f32x4;

struct __align__(8)  half4 { __half x, y, z, w; };
struct __align__(16) half8 { __half h[8]; };

__device__ __forceinline__ unsigned short f2bf(float f) {
    union { float f; unsigned u; } v; v.f = f;
    unsigned r = v.u + 0x7FFFu + ((v.u >> 16) & 1u);   // RNE
    return (unsigned short)(r >> 16);
}
__device__ __forceinline__ float bf2f(unsigned short h) {
    union { unsigned u; float f; } v; v.u = ((unsigned)h) << 16;
    return v.f;
}

// ---------------------------------------------------------------------------
// setup: cursors, W1 -> frag-ordered bf16-split (Wh1/Wl1, 16384 each),
// W2p = W2@Wfc folded+converted (Wh2/Wl2, 48x128 = 6144 each, cols>=40 zero),
// b2p = b2@Wfc + bfc.
// ---------------------------------------------------------------------------
__global__ void setup_kernel(const float* __restrict__ W1, const float* __restrict__ W2,
                             const float* __restrict__ Wfc,
                             const float* __restrict__ b2, const float* __restrict__ bfc,
                             unsigned short* __restrict__ Wh1, unsigned short* __restrict__ Wl1,
                             unsigned short* __restrict__ Wh2, unsigned short* __restrict__ Wl2,
                             float* __restrict__ b2p,
                             int* __restrict__ cur_d, int* __restrict__ cur_s, int nbuck) {
    int idx = blockIdx.x * blockDim.x + threadIdx.x;
    if (idx < nbuck) { cur_d[idx] = idx * SLAB; cur_s[idx] = idx * SLAB; }

    if (idx < 16384) {
        // W1[k][nn] -> frag pos for gemm128
        int k = idx >> 7, nn = idx & 127;
        float v = W1[idx];
        int q = k >> 5, j = k & 7, lb = ((k >> 3) & 3) * 16;
        int tcol = nn >> 4;
        int l = lb + (nn & 15);
        int pos = ((tcol * 4 + q) * 64 + l) * 8 + j;
        unsigned short h = f2bf(v);
        Wh1[pos] = h;
        Wl1[pos] = f2bf(v - bf2f(h));
    } else if (idx < 16384 + 6144) {
        // W2p[k][nn] = dot(W2 row k, Wfc col nn) -> frag pos for fused gemm40
        int i2 = idx - 16384;
        int k = i2 / 48, nn = i2 - k * 48;
        float v = 0.f;
        if (nn < 40) {
            const float* w2row = W2 + k * 128;
            #pragma unroll 8
            for (int jj = 0; jj < 128; ++jj) v += w2row[jj] * Wfc[jj * 40 + nn];
        }
        int t = nn >> 4, q = k >> 5, j = k & 7;
        int l = ((k >> 3) & 3) * 16 + (nn & 15);
        int pos = ((t * 4 + q) * 64 + l) * 8 + j;
        unsigned short h = f2bf(v);
        Wh2[pos] = h;
        Wl2[pos] = f2bf(v - bf2f(h));
    } else if (idx < 16384 + 6144 + 40) {
        int c = idx - (16384 + 6144);
        float a = bfc[c];
        #pragma unroll 8
        for (int j = 0; j < 128; ++j) a += b2[j] * Wfc[j * 40 + c];
        b2p[c] = a;
    }
}

// ------------- single-pass partition with per-bucket slab reservation -------
// buckets = node>>7 (128 nodes each, 782 buckets), 782 LDS bins.
// 1024 threads/block; each thread loads its 4 edges ONCE as int4 and holds
// them in registers across the reservation barrier (R25).
__global__ __launch_bounds__(1024) void scatter_res_kernel(
        const int* __restrict__ src, const int* __restrict__ dst,
        int* __restrict__ cur_d, int* __restrict__ cur_s,
        unsigned int* __restrict__ ppack, unsigned char* __restrict__ es_loc,
        int E) {
    __shared__ int hd[NBK], hs[NBK], bd[NBK], bs[NBK];
    const int tid = threadIdx.x;
    for (int i = tid; i < NBK; i += 1024) { hd[i] = 0; hs[i] = 0; }
    __syncthreads();

    const int base = blockIdx.x * CHUNK;
    const int rem  = min(CHUNK, E - base);     // edges in this chunk
    const int off  = tid * 4;
    int cnt = 0;
    int s0 = 0, s1 = 0, s2 = 0, s3 = 0;
    int d0 = 0, d1 = 0, d2 = 0, d3 = 0;
    if (off < rem) {
        cnt = min(4, rem - off);
        const int e0 = base + off;
        if (cnt == 4) {
            int4 sv = *(const int4*)(src + e0);
            int4 dv = *(const int4*)(dst + e0);
            s0 = sv.x; s1 = sv.y; s2 = sv.z; s3 = sv.w;
            d0 = dv.x; d1 = dv.y; d2 = dv.z; d3 = dv.w;
        } else {
            s0 = src[e0]; d0 = dst[e0];
            if (cnt > 1) { s1 = src[e0 + 1]; d1 = dst[e0 + 1]; }
            if (cnt > 2) { s2 = src[e0 + 2]; d2 = dst[e0 + 2]; }
        }
        // pass 1: LDS histograms (registers only, no re-read)
        atomicAdd(&hd[((unsigned)d0) >> 7], 1);
        atomicAdd(&hs[((unsigned)s0) >> 7], 1);
        if (cnt > 1) { atomicAdd(&hd[((unsigned)d1) >> 7], 1);
                       atomicAdd(&hs[((unsigned)s1) >> 7], 1); }
        if (cnt > 2) { atomicAdd(&hd[((unsigned)d2) >> 7], 1);
                       atomicAdd(&hs[((unsigned)s2) >> 7], 1); }
        if (cnt > 3) { atomicAdd(&hd[((unsigned)d3) >> 7], 1);
                       atomicAdd(&hs[((unsigned)s3) >> 7], 1); }
    }
    __syncthreads();
    for (int i = tid; i < NBK; i += 1024) {
        int cd = hd[i];
        bd[i] = cd ? atomicAdd(&cur_d[i], cd) : 0;
        hd[i] = 0;
        int cs = hs[i];
        bs[i] = cs ? atomicAdd(&cur_s[i], cs) : 0;
        hs[i] = 0;
    }
    __syncthreads();
    if (cnt > 0) {
        #pragma unroll
        for (int k = 0; k < 4; ++k) {
            if (k >= cnt) break;
            int s = (k == 0) ? s0 : (k == 1) ? s1 : (k == 2) ? s2 : s3;
            int d = (k == 0) ? d0 : (k == 1) ? d1 : (k == 2) ? d2 : d3;
            unsigned bin_d = ((unsigned)d) >> 7;
            int pos = bd[bin_d] + atomicAdd(&hd[bin_d], 1);
            ppack[pos] = (((unsigned)d & 127u) << 17) | (unsigned)s;
            unsigned bin_s = ((unsigned)s) >> 7;
            int ps = bs[bin_s] + atomicAdd(&hs[bin_s], 1);
            es_loc[ps] = (unsigned char)(s & 127);
        }
    }
}

// ---------------------------------------------------------------------------
// CO-LAUNCH: fine (even blocks) || unscaled gemm128 (odd blocks).
// nbuck == gemm_grid == ceil(N/128) -> perfect interleave; every CU hosts a
// mix of {slab-streaming fine} and {MFMA-bound gemm} blocks.
// ---------------------------------------------------------------------------
__global__ __launch_bounds__(256, 3) void fine_gemm_kernel(
        const unsigned int* __restrict__ ppack, const int* __restrict__ cur_d,
        const unsigned char* __restrict__ es_loc, const int* __restrict__ cur_s,
        int* __restrict__ deg_in, float* __restrict__ norm_in,
        int* __restrict__ row_ptr, int* __restrict__ csr_src,
        float* __restrict__ norm_out, int N_,
        const float* __restrict__ X,
        const unsigned short* __restrict__ Wh, const unsigned short* __restrict__ Wl,
        __half* __restrict__ Y) {
    const int tid = threadIdx.x;

    if ((blockIdx.x & 1) == 0) {
        // ---------------- fine path (bucket b) ----------------
        __shared__ int h[128];
        __shared__ int psum[128];
        const int b = blockIdx.x >> 1;
        const int start = b * SLAB;
        const int node  = (b << 7) + tid;

        // dst: histogram -> prefix -> CSR scatter
        const int end_d = cur_d[b];
        if (tid < 128) h[tid] = 0;
        __syncthreads();
        for (int i = start + tid; i < end_d; i += 256)
            atomicAdd(&h[ppack[i] >> 17], 1);
        __syncthreads();

        int a = 0;
        if (tid < 128) { a = h[tid]; psum[tid] = a; }
        __syncthreads();
        for (int off = 1; off < 128; off <<= 1) {
            int t = 0;
            if (tid < 128 && tid >= off) t = psum[tid - off];
            __syncthreads();
            if (tid < 128) psum[tid] += t;
            __syncthreads();
        }

        if (tid < 128) {
            int base0 = psum[tid] - a + start;   // slab-local CSR position
            if (node < N_) {
                deg_in[node]  = a;
                row_ptr[node] = base0;
                norm_in[node] = rsqrtf((float)(a < 1 ? 1 : a));
            }
            h[tid] = base0;
        }
        __syncthreads();

        for (int i = start + tid; i < end_d; i += 256) {
            unsigned int pk = ppack[i];
            int pos = atomicAdd(&h[pk >> 17], 1);
            csr_src[pos] = (int)(pk & 0x1FFFFu);
        }
        __syncthreads();

        // src: histogram -> norm_out
        const int end_s = cur_s[b];
        if (tid < 128) h[tid] = 0;
        __syncthreads();
        for (int i = start + tid; i < end_s; i += 256)
            atomicAdd(&h[(int)es_loc[i]], 1);
        __syncthreads();

        if (tid < 128 && node < N_) {
            int d = h[tid];
            norm_out[node] = rsqrtf((float)(d < 1 ? 1 : d));
        }
        return;
    }

    // ---------------- gemm path (unscaled Y = X @ W1) ----------------
    const int blk  = blockIdx.x >> 1;
    const int lane = tid & 63;
    const int w    = tid >> 6;
    const int m    = lane & 15;
    const int quad = lane >> 4;
    const int rowBase = blk * 128 + w * 32;
    const int nrows = N_;

    bf16x8 Ah[2][4], Al[2][4];
    #pragma unroll
    for (int rt = 0; rt < 2; ++rt) {
        int r = rowBase + rt * 16 + m;
        const float* xr = X + (size_t)(r < nrows ? r : 0) * 128;
        const float z = (r < nrows) ? 1.f : 0.f;
        #pragma unroll
        for (int q = 0; q < 4; ++q) {
            int k0 = q * 32 + quad * 8;
            float4 a = *(const float4*)(xr + k0);
            float4 bv = *(const float4*)(xr + k0 + 4);
            float v[8] = {a.x * z, a.y * z, a.z * z, a.w * z,
                          bv.x * z, bv.y * z, bv.z * z, bv.w * z};
            bf16x8 hi, lo;
            #pragma unroll
            for (int j = 0; j < 8; ++j) {
                unsigned short h = f2bf(v[j]);
                hi[j] = (short)h;
                lo[j] = (short)f2bf(v[j] - bf2f(h));
            }
            Ah[rt][q] = hi; Al[rt][q] = lo;
        }
    }

    f32x4 acc[2][8];
    #pragma unroll
    for (int rt = 0; rt < 2; ++rt)
        #pragma unroll
        for (int t = 0; t < 8; ++t)
            acc[rt][t] = (f32x4){0.f, 0.f, 0.f, 0.f};

    #pragma unroll
    for (int t = 0; t < 8; ++t) {
        #pragma unroll
        for (int q = 0; q < 4; ++q) {
            const int off = ((t * 4 + q) * 64 + lane) * 8;
            bf16x8 Bh = *(const bf16x8*)(Wh + off);
            bf16x8 Bl = *(const bf16x8*)(Wl + off);
            #pragma unroll
            for (int rt = 0; rt < 2; ++rt) {
                acc[rt][t] = __builtin_amdgcn_mfma_f32_16x16x32_bf16(Ah[rt][q], Bh, acc[rt][t], 0, 0, 0);
                acc[rt][t] = __builtin_amdgcn_mfma_f32_16x16x32_bf16(Ah[rt][q], Bl, acc[rt][t], 0, 0, 0);
                acc[rt][t] = __builtin_amdgcn_mfma_f32_16x16x32_bf16(Al[rt][q], Bh, acc[rt][t], 0, 0, 0);
            }
        }
    }

    #pragma unroll
    for (int rt = 0; rt < 2; ++rt) {
        int r0 = rowBase + rt * 16 + quad * 4;
        #pragma unroll
        for (int reg = 0; reg < 4; ++reg) {
            int r = r0 + reg;
            if (r >= nrows) continue;
            __half* yr = Y + (size_t)r * 128 + m;
            #pragma unroll
            for (int t = 0; t < 8; ++t)
                yr[t * 16] = __float2half(acc[rt][t][reg]);
        }
    }
}

// ---------------------------------------------------------------------------
// FUSED WEIGHTED gather + layer-1 GEMM.
// Phase 1 (all 256 threads): h1[node] = relu((sum_s no[s]*Y[s]) * ni + b1)
//   (Y is UNSCALED X@W1; norm_out applied per-edge, table L2-hot), then
//   pre-scaled by norm_out[node] and SPLIT to bf16 hi/lo in LDS.
// Phase 2 (waves 0-2): pure ds_read_b128 A-frags + 12 MFMA -> G[16 x 40].
// h1 never touches global memory.
// ---------------------------------------------------------------------------
__global__ __launch_bounds__(256, 4) void gather_kernel(
        const __half* __restrict__ H, const int* __restrict__ row_ptr,
        const int* __restrict__ deg, const int* __restrict__ csr_src,
        const float* __restrict__ norm_in, const float* __restrict__ b,
        const float* __restrict__ norm_out,
        const unsigned short* __restrict__ Wh2, const unsigned short* __restrict__ Wl2,
        __half* __restrict__ G, int n) {
    __shared__ unsigned short h1h[16][136];   // bf16 hi, stride 136 (2-way alias max)
    __shared__ unsigned short h1l[16][136];   // bf16 lo
    const int tid   = threadIdx.x;
    const int node0 = blockIdx.x * 16;
    const int g     = tid >> 4;              // node-in-block 0..15
    const int node  = node0 + g;
    const int c     = (tid & 15) * 8;        // column group
    const bool active = node < n;

    int start = 0, cnt = 0;
    if (active) { start = row_ptr[node]; cnt = deg[node]; }
    float acc[8] = {0.f, 0.f, 0.f, 0.f, 0.f, 0.f, 0.f, 0.f};

    int j = 0;
    for (; j + 4 <= cnt; j += 4) {
        int s0 = csr_src[start + j];
        int s1 = csr_src[start + j + 1];
        int s2 = csr_src[start + j + 2];
        int s3 = csr_src[start + j + 3];
        float n0 = norm_out[s0], n1 = norm_out[s1];
        float n2 = norm_out[s2], n3 = norm_out[s3];
        half8 v0 = *(const half8*)(H + (long long)s0 * 128 + c);
        half8 v1 = *(const half8*)(H + (long long)s1 * 128 + c);
        half8 v2 = *(const half8*)(H + (long long)s2 * 128 + c);
        half8 v3 = *(const half8*)(H + (long long)s3 * 128 + c);
        #pragma unroll
        for (int k = 0; k < 8; ++k) {
            float t0 = fmaf(n0, __half2float(v0.h[k]), fmaf(n1, __half2float(v1.h[k]), acc[k]));
            acc[k] = fmaf(n2, __half2float(v2.h[k]), fmaf(n3, __half2float(v3.h[k]), t0));
        }
    }
    for (; j < cnt; ++j) {
        int s0 = csr_src[start + j];
        float n0 = norm_out[s0];
        half8 v0 = *(const half8*)(H + (long long)s0 * 128 + c);
        #pragma unroll
        for (int k = 0; k < 8; ++k) acc[k] = fmaf(n0, __half2float(v0.h[k]), acc[k]);
    }

    float ni = active ? norm_in[node]  : 0.f;
    float no = active ? norm_out[node] : 0.f;   // layer-1 row scale, pre-applied
    float4 b0  = *(const float4*)(b + c);
    float4 b1v = *(const float4*)(b + c + 4);
    float bb[8] = {b0.x, b0.y, b0.z, b0.w, b1v.x, b1v.y, b1v.z, b1v.w};
    bf16x8 hi, lo;
    #pragma unroll
    for (int k = 0; k < 8; ++k) {
        float hv = fmaxf(acc[k] * ni + bb[k], 0.f) * no;
        unsigned short h = f2bf(hv);
        hi[k] = (short)h;
        lo[k] = (short)f2bf(hv - bf2f(h));
    }
    *(bf16x8*)&h1h[g][c] = hi;
    *(bf16x8*)&h1l[g][c] = lo;
    __syncthreads();

    // phase 2: waves 0..2 each compute one 16-col tile of G (pure LDS+MFMA)
    const int w = tid >> 6;
    if (w < 3) {
        const int lane = tid & 63;
        const int m    = lane & 15;
        const int quad = lane >> 4;

        f32x4 a3 = (f32x4){0.f, 0.f, 0.f, 0.f};
        const int t = w;
        #pragma unroll
        for (int q = 0; q < 4; ++q) {
            const int k0 = q * 32 + quad * 8;
            bf16x8 Ah = *(const bf16x8*)&h1h[m][k0];
            bf16x8 Al = *(const bf16x8*)&h1l[m][k0];
            const int off = ((t * 4 + q) * 64 + lane) * 8;
            bf16x8 Bh = *(const bf16x8*)(Wh2 + off);
            bf16x8 Bl = *(const bf16x8*)(Wl2 + off);
            a3 = __builtin_amdgcn_mfma_f32_16x16x32_bf16(Ah, Bh, a3, 0, 0, 0);
            a3 = __builtin_amdgcn_mfma_f32_16x16x32_bf16(Ah, Bl, a3, 0, 0, 0);
            a3 = __builtin_amdgcn_mfma_f32_16x16x32_bf16(Al, Bh, a3, 0, 0, 0);
        }

        const int col = t * 16 + m;
        if (col < 40) {
            const int r0 = node0 + quad * 4;
            #pragma unroll
            for (int reg = 0; reg < 4; ++reg) {
                int r = r0 + reg;
                if (r < n) G[(size_t)r * 64 + col] = __float2half(a3[reg]);
            }
        }
    }
}

// 40-dim gather (fp16 in, PADDED stride 64; fp32 out): out = (sum G[src])*ni + b2p
// 5 lanes per node, one half8 (16 B) each.
__global__ __launch_bounds__(256) void gather40_kernel(
        const __half* __restrict__ G, const int* __restrict__ row_ptr,
        const int* __restrict__ deg, const int* __restrict__ csr_src,
        const float* __restrict__ norm_in, const float* __restrict__ b2p,
        float* __restrict__ out, int n) {
    const int t = blockIdx.x * 256 + threadIdx.x;
    if (t >= n * 5) return;
    const int node = t / 5;
    const int c    = (t - node * 5) * 8;

    const int start = row_ptr[node];
    const int cnt   = deg[node];
    float acc[8] = {0.f, 0.f, 0.f, 0.f, 0.f, 0.f, 0.f, 0.f};

    int j = 0;
    for (; j + 4 <= cnt; j += 4) {
        int s0 = csr_src[start + j];
        int s1 = csr_src[start + j + 1];
        int s2 = csr_src[start + j + 2];
        int s3 = csr_src[start + j + 3];
        half8 v0 = *(const half8*)(G + (long long)s0 * 64 + c);
        half8 v1 = *(const half8*)(G + (long long)s1 * 64 + c);
        half8 v2 = *(const half8*)(G + (long long)s2 * 64 + c);
        half8 v3 = *(const half8*)(G + (long long)s3 * 64 + c);
        #pragma unroll
        for (int k = 0; k < 8; ++k)
            acc[k] += (__half2float(v0.h[k]) + __half2float(v1.h[k]))
                    + (__half2float(v2.h[k]) + __half2float(v3.h[k]));
    }
    for (; j < cnt; ++j) {
        int s0 = csr_src[start + j];
        half8 v0 = *(const half8*)(G + (long long)s0 * 64 + c);
        #pragma unroll
        for (int k = 0; k < 8; ++k) acc[k] += __half2float(v0.h[k]);
    }

    float ni = norm_in[node];
    float4 o0, o1;
    o0.x = acc[0] * ni + b2p[c + 0];
    o0.y = acc[1] * ni + b2p[c + 1];
    o0.z = acc[2] * ni + b2p[c + 2];
    o0.w = acc[3] * ni + b2p[c + 3];
    o1.x = acc[4] * ni + b2p[c + 4];
    o1.y = acc[5] * ni + b2p[c + 5];
    o1.z = acc[6] * ni + b2p[c + 6];
    o1.w = acc[7] * ni + b2p[c + 7];
    float* op = out + (long long)node * 40 + c;
    *(float4*)(op)     = o0;
    *(float4*)(op + 4) = o1;
}

extern "C" void kernel_launch(void* const* d_in, const int* in_sizes, int n_in,
                              void* d_out, int out_size, void* d_ws, size_t ws_size,
                              hipStream_t stream) {
    const float* x   = (const float*)d_in[0];
    const int*   ei  = (const int*)  d_in[1];
    const float* W1  = (const float*)d_in[2];
    const float* b1  = (const float*)d_in[3];
    const float* W2  = (const float*)d_in[4];
    const float* b2  = (const float*)d_in[5];
    const float* Wfc = (const float*)d_in[6];
    const float* bfc = (const float*)d_in[7];
    float* out = (float*)d_out;

    const int N = in_sizes[0] / 128;
    const int E = in_sizes[1] / 2;
    const int* src = ei;
    const int* dst = ei + E;

    const int nbuck = (N + 127) >> 7;                  // 782 (== gemm grid)
    const int B1 = (E + CHUNK - 1) / CHUNK;            // 391 scatter blocks

    char* p = (char*)d_ws;
    float* norm_out = (float*)p; p += (size_t)N * 4;
    float* norm_in  = (float*)p; p += (size_t)N * 4;
    float* bufA     = (float*)p; p += (size_t)N * 128 * 4;   // h1pre fp16
    float* bufB     = (float*)p; p += (size_t)N * 128 * 4;   // slabs, then G fp16
    int*   deg_in   = (int*)p;   p += (size_t)N * 4;
    int*   row_ptr  = (int*)p;   p += (size_t)N * 4;
    int*   csr_src  = (int*)p;   p += (size_t)NBK * SLAB * 4;   // slab-indexed CSR
    int*   cur_d    = (int*)p;   p += (size_t)1024 * 4;
    int*   cur_s    = (int*)p;   p += (size_t)1024 * 4;
    float* b2p      = (float*)p; p += (size_t)64 * 4;
    unsigned short* Wh1 = (unsigned short*)p; p += (size_t)16384 * 2;
    unsigned short* Wl1 = (unsigned short*)p; p += (size_t)16384 * 2;
    unsigned short* Wh2 = (unsigned short*)p; p += (size_t)6144 * 2;
    unsigned short* Wl2 = (unsigned short*)p; p += (size_t)6144 * 2;

    // partition slabs alias bufB (consumed by fine before gather writes G)
    unsigned int*  ppack  = (unsigned int*)bufB;
    unsigned char* es_loc = (unsigned char*)(ppack + (size_t)NBK * SLAB);

    __half* h1pre = (__half*)bufA;   // N x 128 fp16 (UNSCALED X@W1)
    __half* G     = (__half*)bufB;   // N x 64 fp16 PADDED (fused-gather output)

    const int T = 256;

    // setup: cursors + W1/W2p frag conversion + b2p
    setup_kernel<<<(16384 + 6144 + 40 + T - 1) / T, T, 0, stream>>>(
        W1, W2, Wfc, b2, bfc, Wh1, Wl1, Wh2, Wl2, b2p, cur_d, cur_s, nbuck);
    // partition (1024-thread blocks, int4 register-held edges)
    scatter_res_kernel<<<B1, 1024, 0, stream>>>(src, dst, cur_d, cur_s,
                                                ppack, es_loc, E);
    // CO-LAUNCH: fine (even) || unscaled gemm128 (odd), perfectly interleaved
    fine_gemm_kernel<<<2 * nbuck, T, 0, stream>>>(
        ppack, cur_d, es_loc, cur_s, deg_in, norm_in, row_ptr, csr_src,
        norm_out, N, x, Wh1, Wl1, h1pre);
    // fused weighted gather: sum no[s]*Y[s] -> relu -> (h1*no)@W2p -> G
    const int gather_grid = (N + 15) / 16;
    gather_kernel<<<gather_grid, T, 0, stream>>>(h1pre, row_ptr, deg_in, csr_src,
                                                 norm_in, b1, norm_out,
                                                 Wh2, Wl2, G, N);
    // final gather + bias: out = gather(G) * ni + b2p
    gather40_kernel<<<((size_t)N * 5 + T - 1) / T, T, 0, stream>>>(
        G, row_ptr, deg_in, csr_src, norm_in, b2p, out, N);
}

// Round 15
// 264.913 us; speedup vs baseline: 1.1700x; 1.0225x over previous
//
#include <hip/hip_runtime.h>
#include <hip/hip_fp16.h>

// ---------------------------------------------------------------------------
// GCN: 2x GraphConv (norm='both') + FC.  fp32 math, fp16 intermediates.
// R2..R8: 5943 -> 325 us (CSR gather, fold FC, MFMA GEMMs, fp16, no atomics).
// R9-R11: reservation partition, lane tuning. 323 us.
// R12/R13: XCD-affinity sliced gather. REGRESSED: per-XCD L2 replication of
//      shared tables is structural (gather FETCH 178 MB == 8 x 22 MB
//      compulsory; rate ~3.1-3.6 TB/s == miss-concurrency cap).
// R14: pad G rows to 128B + merged 512-node fine pass. 314.7 us.
// R15: W-frag preconversion; GEMMs LDS-free. 297.9 us.
// R16: 128-node buckets (fine faster, but scatter slab runs -> 21B partial
//      lines). 290.0 us.
// R17: fused gemm40 into gather epilogue (h1 never hits HBM). 279.1 us.
// R18: gather pre-splits bf16 into LDS (KEPT); gemm128 64-row REGRESSED.
// R19: best-of-each recombination. 277.5 us.
// R20/R24: direct global deg_out atomics REGRESSED BOTH TIMES: cross-XCD
//      coherence serializes random device-scope atomics. RULE: LDS histograms.
// R21: 1024-thread scatter: -2.4 us. 275.1 us.
// R22: scatter||gemm co-launch NEUTRAL (gemm starved scatter's waves).
// R23: fine||gemm co-launch WIN. 271.0 us.
// R25: int4 register-held scatter edges NEUTRAL (270.9) -> scatter is
//      LDS-atomic/store-bound, not VMEM-bound.
// R26: reverse R16 for scatter only: 512-node buckets (196) -> slab runs
//      4x longer (84B ppack / 42B es_loc, ~4x less write amplification);
//      fine returns to proven R14 512-node form (196 blocks) whose 4x work
//      hides under the gemm co-launch (R23 mechanism). es_loc -> ushort.
// ---------------------------------------------------------------------------

#define CHUNK    4096   // edges per scatter block (391 blocks)
#define NBC      256    // coarse bin array (>= nbuck=196)
#define SLAB     9216   // per-bucket slab capacity (mean 8163 + ~11 sigma)

typedef __attribute__((ext_vector_type(8))) short bf16x8;
typedef __attribute__((ext_vector_type(4))) float f32x4;

struct __align__(8)  half4 { __half x, y, z, w; };
struct __align__(16) half8 { __half h[8]; };

__device__ __forceinline__ unsigned short f2bf(float f) {
    union { float f; unsigned u; } v; v.f = f;
    unsigned r = v.u + 0x7FFFu + ((v.u >> 16) & 1u);   // RNE
    return (unsigned short)(r >> 16);
}
__device__ __forceinline__ float bf2f(unsigned short h) {
    union { unsigned u; float f; } v; v.u = ((unsigned)h) << 16;
    return v.f;
}

// ---------------------------------------------------------------------------
// setup: cursors, W1 -> frag-ordered bf16-split (Wh1/Wl1, 16384 each),
// W2p = W2@Wfc folded+converted (Wh2/Wl2, 48x128 = 6144 each, cols>=40 zero),
// b2p = b2@Wfc + bfc.
// ---------------------------------------------------------------------------
__global__ void setup_kernel(const float* __restrict__ W1, const float* __restrict__ W2,
                             const float* __restrict__ Wfc,
                             const float* __restrict__ b2, const float* __restrict__ bfc,
                             unsigned short* __restrict__ Wh1, unsigned short* __restrict__ Wl1,
                             unsigned short* __restrict__ Wh2, unsigned short* __restrict__ Wl2,
                             float* __restrict__ b2p,
                             int* __restrict__ cur_d, int* __restrict__ cur_s, int nbuck) {
    int idx = blockIdx.x * blockDim.x + threadIdx.x;
    if (idx < nbuck) { cur_d[idx] = idx * SLAB; cur_s[idx] = idx * SLAB; }

    if (idx < 16384) {
        // W1[k][nn] -> frag pos for gemm128
        int k = idx >> 7, nn = idx & 127;
        float v = W1[idx];
        int q = k >> 5, j = k & 7, lb = ((k >> 3) & 3) * 16;
        int tcol = nn >> 4;
        int l = lb + (nn & 15);
        int pos = ((tcol * 4 + q) * 64 + l) * 8 + j;
        unsigned short h = f2bf(v);
        Wh1[pos] = h;
        Wl1[pos] = f2bf(v - bf2f(h));
    } else if (idx < 16384 + 6144) {
        // W2p[k][nn] = dot(W2 row k, Wfc col nn) -> frag pos for fused gemm40
        int i2 = idx - 16384;
        int k = i2 / 48, nn = i2 - k * 48;
        float v = 0.f;
        if (nn < 40) {
            const float* w2row = W2 + k * 128;
            #pragma unroll 8
            for (int jj = 0; jj < 128; ++jj) v += w2row[jj] * Wfc[jj * 40 + nn];
        }
        int t = nn >> 4, q = k >> 5, j = k & 7;
        int l = ((k >> 3) & 3) * 16 + (nn & 15);
        int pos = ((t * 4 + q) * 64 + l) * 8 + j;
        unsigned short h = f2bf(v);
        Wh2[pos] = h;
        Wl2[pos] = f2bf(v - bf2f(h));
    } else if (idx < 16384 + 6144 + 40) {
        int c = idx - (16384 + 6144);
        float a = bfc[c];
        #pragma unroll 8
        for (int j = 0; j < 128; ++j) a += b2[j] * Wfc[j * 40 + c];
        b2p[c] = a;
    }
}

// ------------- single-pass partition with per-bucket slab reservation -------
// COARSE buckets = node>>9 (512 nodes, 196 buckets): slab runs ~21 entries
// (84B ppack / 42B es_loc) per bucket per block -> ~4x less partial-line
// write amplification than 128-node bins. 1024 threads, int4 register-held
// edges (R25 form). LDS 4 x 256 x 4B = 4KB.
__global__ __launch_bounds__(1024) void scatter_res_kernel(
        const int* __restrict__ src, const int* __restrict__ dst,
        int* __restrict__ cur_d, int* __restrict__ cur_s,
        unsigned int* __restrict__ ppack, unsigned short* __restrict__ es_loc,
        int E) {
    __shared__ int hd[NBC], hs[NBC], bd[NBC], bs[NBC];
    const int tid = threadIdx.x;
    if (tid < NBC) { hd[tid] = 0; hs[tid] = 0; }
    __syncthreads();

    const int base = blockIdx.x * CHUNK;
    const int rem  = min(CHUNK, E - base);     // edges in this chunk
    const int off  = tid * 4;
    int cnt = 0;
    int s0 = 0, s1 = 0, s2 = 0, s3 = 0;
    int d0 = 0, d1 = 0, d2 = 0, d3 = 0;
    if (off < rem) {
        cnt = min(4, rem - off);
        const int e0 = base + off;
        if (cnt == 4) {
            int4 sv = *(const int4*)(src + e0);
            int4 dv = *(const int4*)(dst + e0);
            s0 = sv.x; s1 = sv.y; s2 = sv.z; s3 = sv.w;
            d0 = dv.x; d1 = dv.y; d2 = dv.z; d3 = dv.w;
        } else {
            s0 = src[e0]; d0 = dst[e0];
            if (cnt > 1) { s1 = src[e0 + 1]; d1 = dst[e0 + 1]; }
            if (cnt > 2) { s2 = src[e0 + 2]; d2 = dst[e0 + 2]; }
        }
        // pass 1: LDS histograms (registers only, no re-read)
        atomicAdd(&hd[((unsigned)d0) >> 9], 1);
        atomicAdd(&hs[((unsigned)s0) >> 9], 1);
        if (cnt > 1) { atomicAdd(&hd[((unsigned)d1) >> 9], 1);
                       atomicAdd(&hs[((unsigned)s1) >> 9], 1); }
        if (cnt > 2) { atomicAdd(&hd[((unsigned)d2) >> 9], 1);
                       atomicAdd(&hs[((unsigned)s2) >> 9], 1); }
        if (cnt > 3) { atomicAdd(&hd[((unsigned)d3) >> 9], 1);
                       atomicAdd(&hs[((unsigned)s3) >> 9], 1); }
    }
    __syncthreads();
    if (tid < NBC) {
        int cd = hd[tid];
        bd[tid] = cd ? atomicAdd(&cur_d[tid], cd) : 0;
        hd[tid] = 0;
        int cs = hs[tid];
        bs[tid] = cs ? atomicAdd(&cur_s[tid], cs) : 0;
        hs[tid] = 0;
    }
    __syncthreads();
    if (cnt > 0) {
        #pragma unroll
        for (int k = 0; k < 4; ++k) {
            if (k >= cnt) break;
            int s = (k == 0) ? s0 : (k == 1) ? s1 : (k == 2) ? s2 : s3;
            int d = (k == 0) ? d0 : (k == 1) ? d1 : (k == 2) ? d2 : d3;
            unsigned bin_d = ((unsigned)d) >> 9;
            int pos = bd[bin_d] + atomicAdd(&hd[bin_d], 1);
            ppack[pos] = (((unsigned)d & 511u) << 17) | (unsigned)s;
            unsigned bin_s = ((unsigned)s) >> 9;
            int ps = bs[bin_s] + atomicAdd(&hs[bin_s], 1);
            es_loc[ps] = (unsigned short)(s & 511);
        }
    }
}

// ---------------------------------------------------------------------------
// CO-LAUNCH: fine (blocks [0,nfine), R14 512-node form) || unscaled gemm128
// (blocks [nfine, nfine+gemmgrid)). Round-robin dispatch mixes both types
// per CU; fine's 4x-longer blocks hide under the gemm MFMA wall.
// ---------------------------------------------------------------------------
__global__ __launch_bounds__(256, 3) void fine_gemm_kernel(
        const unsigned int* __restrict__ ppack, const int* __restrict__ cur_d,
        const unsigned short* __restrict__ es_loc, const int* __restrict__ cur_s,
        int* __restrict__ deg_in, float* __restrict__ norm_in,
        int* __restrict__ row_ptr, int* __restrict__ csr_src,
        float* __restrict__ norm_out, int N_, int nfine,
        const float* __restrict__ X,
        const unsigned short* __restrict__ Wh, const unsigned short* __restrict__ Wl,
        __half* __restrict__ Y) {
    const int tid = threadIdx.x;

    if (blockIdx.x < nfine) {
        // ---------------- fine path (512-node bucket b, R14 form) ----------
        __shared__ int h[512];
        __shared__ int psum[256];
        const int b = blockIdx.x;
        const int start = b * SLAB;
        const int node0 = b << 9;

        // dst: histogram -> prefix -> CSR scatter
        const int end_d = cur_d[b];
        h[tid] = 0; h[tid + 256] = 0;
        __syncthreads();
        for (int i = start + tid; i < end_d; i += 256)
            atomicAdd(&h[ppack[i] >> 17], 1);
        __syncthreads();

        int a0 = h[2 * tid], a1 = h[2 * tid + 1];
        int pair = a0 + a1;
        psum[tid] = pair;
        __syncthreads();
        for (int off = 1; off < 256; off <<= 1) {
            int t = (tid >= off) ? psum[tid - off] : 0;
            __syncthreads();
            psum[tid] += t;
            __syncthreads();
        }
        int base0 = psum[tid] - pair + start;   // slab-local CSR position

        int n0 = node0 + 2 * tid, n1 = n0 + 1;
        if (n0 < N_) {
            deg_in[n0]  = a0;
            row_ptr[n0] = base0;
            norm_in[n0] = rsqrtf((float)(a0 < 1 ? 1 : a0));
        }
        if (n1 < N_) {
            deg_in[n1]  = a1;
            row_ptr[n1] = base0 + a0;
            norm_in[n1] = rsqrtf((float)(a1 < 1 ? 1 : a1));
        }
        h[2 * tid]     = base0;
        h[2 * tid + 1] = base0 + a0;
        __syncthreads();

        for (int i = start + tid; i < end_d; i += 256) {
            unsigned int pk = ppack[i];
            int pos = atomicAdd(&h[pk >> 17], 1);
            csr_src[pos] = (int)(pk & 0x1FFFFu);
        }
        __syncthreads();

        // src: histogram -> norm_out
        const int end_s = cur_s[b];
        h[tid] = 0; h[tid + 256] = 0;
        __syncthreads();
        for (int i = start + tid; i < end_s; i += 256)
            atomicAdd(&h[(int)es_loc[i]], 1);
        __syncthreads();

        int m0 = node0 + tid, m1 = m0 + 256;
        if (m0 < N_) { int d = h[tid];       norm_out[m0] = rsqrtf((float)(d < 1 ? 1 : d)); }
        if (m1 < N_) { int d = h[tid + 256]; norm_out[m1] = rsqrtf((float)(d < 1 ? 1 : d)); }
        return;
    }

    // ---------------- gemm path (unscaled Y = X @ W1) ----------------
    const int blk  = blockIdx.x - nfine;
    const int lane = tid & 63;
    const int w    = tid >> 6;
    const int m    = lane & 15;
    const int quad = lane >> 4;
    const int rowBase = blk * 128 + w * 32;
    const int nrows = N_;

    bf16x8 Ah[2][4], Al[2][4];
    #pragma unroll
    for (int rt = 0; rt < 2; ++rt) {
        int r = rowBase + rt * 16 + m;
        const float* xr = X + (size_t)(r < nrows ? r : 0) * 128;
        const float z = (r < nrows) ? 1.f : 0.f;
        #pragma unroll
        for (int q = 0; q < 4; ++q) {
            int k0 = q * 32 + quad * 8;
            float4 a = *(const float4*)(xr + k0);
            float4 bv = *(const float4*)(xr + k0 + 4);
            float v[8] = {a.x * z, a.y * z, a.z * z, a.w * z,
                          bv.x * z, bv.y * z, bv.z * z, bv.w * z};
            bf16x8 hi, lo;
            #pragma unroll
            for (int j = 0; j < 8; ++j) {
                unsigned short h = f2bf(v[j]);
                hi[j] = (short)h;
                lo[j] = (short)f2bf(v[j] - bf2f(h));
            }
            Ah[rt][q] = hi; Al[rt][q] = lo;
        }
    }

    f32x4 acc[2][8];
    #pragma unroll
    for (int rt = 0; rt < 2; ++rt)
        #pragma unroll
        for (int t = 0; t < 8; ++t)
            acc[rt][t] = (f32x4){0.f, 0.f, 0.f, 0.f};

    #pragma unroll
    for (int t = 0; t < 8; ++t) {
        #pragma unroll
        for (int q = 0; q < 4; ++q) {
            const int off = ((t * 4 + q) * 64 + lane) * 8;
            bf16x8 Bh = *(const bf16x8*)(Wh + off);
            bf16x8 Bl = *(const bf16x8*)(Wl + off);
            #pragma unroll
            for (int rt = 0; rt < 2; ++rt) {
                acc[rt][t] = __builtin_amdgcn_mfma_f32_16x16x32_bf16(Ah[rt][q], Bh, acc[rt][t], 0, 0, 0);
                acc[rt][t] = __builtin_amdgcn_mfma_f32_16x16x32_bf16(Ah[rt][q], Bl, acc[rt][t], 0, 0, 0);
                acc[rt][t] = __builtin_amdgcn_mfma_f32_16x16x32_bf16(Al[rt][q], Bh, acc[rt][t], 0, 0, 0);
            }
        }
    }

    #pragma unroll
    for (int rt = 0; rt < 2; ++rt) {
        int r0 = rowBase + rt * 16 + quad * 4;
        #pragma unroll
        for (int reg = 0; reg < 4; ++reg) {
            int r = r0 + reg;
            if (r >= nrows) continue;
            __half* yr = Y + (size_t)r * 128 + m;
            #pragma unroll
            for (int t = 0; t < 8; ++t)
                yr[t * 16] = __float2half(acc[rt][t][reg]);
        }
    }
}

// ---------------------------------------------------------------------------
// FUSED WEIGHTED gather + layer-1 GEMM.
// Phase 1 (all 256 threads): h1[node] = relu((sum_s no[s]*Y[s]) * ni + b1)
//   (Y is UNSCALED X@W1; norm_out applied per-edge, table L2-hot), then
//   pre-scaled by norm_out[node] and SPLIT to bf16 hi/lo in LDS.
// Phase 2 (waves 0-2): pure ds_read_b128 A-frags + 12 MFMA -> G[16 x 40].
// h1 never touches global memory.
// ---------------------------------------------------------------------------
__global__ __launch_bounds__(256, 4) void gather_kernel(
        const __half* __restrict__ H, const int* __restrict__ row_ptr,
        const int* __restrict__ deg, const int* __restrict__ csr_src,
        const float* __restrict__ norm_in, const float* __restrict__ b,
        const float* __restrict__ norm_out,
        const unsigned short* __restrict__ Wh2, const unsigned short* __restrict__ Wl2,
        __half* __restrict__ G, int n) {
    __shared__ unsigned short h1h[16][136];   // bf16 hi, stride 136 (2-way alias max)
    __shared__ unsigned short h1l[16][136];   // bf16 lo
    const int tid   = threadIdx.x;
    const int node0 = blockIdx.x * 16;
    const int g     = tid >> 4;              // node-in-block 0..15
    const int node  = node0 + g;
    const int c     = (tid & 15) * 8;        // column group
    const bool active = node < n;

    int start = 0, cnt = 0;
    if (active) { start = row_ptr[node]; cnt = deg[node]; }
    float acc[8] = {0.f, 0.f, 0.f, 0.f, 0.f, 0.f, 0.f, 0.f};

    int j = 0;
    for (; j + 4 <= cnt; j += 4) {
        int s0 = csr_src[start + j];
        int s1 = csr_src[start + j + 1];
        int s2 = csr_src[start + j + 2];
        int s3 = csr_src[start + j + 3];
        float n0 = norm_out[s0], n1 = norm_out[s1];
        float n2 = norm_out[s2], n3 = norm_out[s3];
        half8 v0 = *(const half8*)(H + (long long)s0 * 128 + c);
        half8 v1 = *(const half8*)(H + (long long)s1 * 128 + c);
        half8 v2 = *(const half8*)(H + (long long)s2 * 128 + c);
        half8 v3 = *(const half8*)(H + (long long)s3 * 128 + c);
        #pragma unroll
        for (int k = 0; k < 8; ++k) {
            float t0 = fmaf(n0, __half2float(v0.h[k]), fmaf(n1, __half2float(v1.h[k]), acc[k]));
            acc[k] = fmaf(n2, __half2float(v2.h[k]), fmaf(n3, __half2float(v3.h[k]), t0));
        }
    }
    for (; j < cnt; ++j) {
        int s0 = csr_src[start + j];
        float n0 = norm_out[s0];
        half8 v0 = *(const half8*)(H + (long long)s0 * 128 + c);
        #pragma unroll
        for (int k = 0; k < 8; ++k) acc[k] = fmaf(n0, __half2float(v0.h[k]), acc[k]);
    }

    float ni = active ? norm_in[node]  : 0.f;
    float no = active ? norm_out[node] : 0.f;   // layer-1 row scale, pre-applied
    float4 b0  = *(const float4*)(b + c);
    float4 b1v = *(const float4*)(b + c + 4);
    float bb[8] = {b0.x, b0.y, b0.z, b0.w, b1v.x, b1v.y, b1v.z, b1v.w};
    bf16x8 hi, lo;
    #pragma unroll
    for (int k = 0; k < 8; ++k) {
        float hv = fmaxf(acc[k] * ni + bb[k], 0.f) * no;
        unsigned short h = f2bf(hv);
        hi[k] = (short)h;
        lo[k] = (short)f2bf(hv - bf2f(h));
    }
    *(bf16x8*)&h1h[g][c] = hi;
    *(bf16x8*)&h1l[g][c] = lo;
    __syncthreads();

    // phase 2: waves 0..2 each compute one 16-col tile of G (pure LDS+MFMA)
    const int w = tid >> 6;
    if (w < 3) {
        const int lane = tid & 63;
        const int m    = lane & 15;
        const int quad = lane >> 4;

        f32x4 a3 = (f32x4){0.f, 0.f, 0.f, 0.f};
        const int t = w;
        #pragma unroll
        for (int q = 0; q < 4; ++q) {
            const int k0 = q * 32 + quad * 8;
            bf16x8 Ah = *(const bf16x8*)&h1h[m][k0];
            bf16x8 Al = *(const bf16x8*)&h1l[m][k0];
            const int off = ((t * 4 + q) * 64 + lane) * 8;
            bf16x8 Bh = *(const bf16x8*)(Wh2 + off);
            bf16x8 Bl = *(const bf16x8*)(Wl2 + off);
            a3 = __builtin_amdgcn_mfma_f32_16x16x32_bf16(Ah, Bh, a3, 0, 0, 0);
            a3 = __builtin_amdgcn_mfma_f32_16x16x32_bf16(Ah, Bl, a3, 0, 0, 0);
            a3 = __builtin_amdgcn_mfma_f32_16x16x32_bf16(Al, Bh, a3, 0, 0, 0);
        }

        const int col = t * 16 + m;
        if (col < 40) {
            const int r0 = node0 + quad * 4;
            #pragma unroll
            for (int reg = 0; reg < 4; ++reg) {
                int r = r0 + reg;
                if (r < n) G[(size_t)r * 64 + col] = __float2half(a3[reg]);
            }
        }
    }
}

// 40-dim gather (fp16 in, PADDED stride 64; fp32 out): out = (sum G[src])*ni + b2p
// 5 lanes per node, one half8 (16 B) each.
__global__ __launch_bounds__(256) void gather40_kernel(
        const __half* __restrict__ G, const int* __restrict__ row_ptr,
        const int* __restrict__ deg, const int* __restrict__ csr_src,
        const float* __restrict__ norm_in, const float* __restrict__ b2p,
        float* __restrict__ out, int n) {
    const int t = blockIdx.x * 256 + threadIdx.x;
    if (t >= n * 5) return;
    const int node = t / 5;
    const int c    = (t - node * 5) * 8;

    const int start = row_ptr[node];
    const int cnt   = deg[node];
    float acc[8] = {0.f, 0.f, 0.f, 0.f, 0.f, 0.f, 0.f, 0.f};

    int j = 0;
    for (; j + 4 <= cnt; j += 4) {
        int s0 = csr_src[start + j];
        int s1 = csr_src[start + j + 1];
        int s2 = csr_src[start + j + 2];
        int s3 = csr_src[start + j + 3];
        half8 v0 = *(const half8*)(G + (long long)s0 * 64 + c);
        half8 v1 = *(const half8*)(G + (long long)s1 * 64 + c);
        half8 v2 = *(const half8*)(G + (long long)s2 * 64 + c);
        half8 v3 = *(const half8*)(G + (long long)s3 * 64 + c);
        #pragma unroll
        for (int k = 0; k < 8; ++k)
            acc[k] += (__half2float(v0.h[k]) + __half2float(v1.h[k]))
                    + (__half2float(v2.h[k]) + __half2float(v3.h[k]));
    }
    for (; j < cnt; ++j) {
        int s0 = csr_src[start + j];
        half8 v0 = *(const half8*)(G + (long long)s0 * 64 + c);
        #pragma unroll
        for (int k = 0; k < 8; ++k) acc[k] += __half2float(v0.h[k]);
    }

    float ni = norm_in[node];
    float4 o0, o1;
    o0.x = acc[0] * ni + b2p[c + 0];
    o0.y = acc[1] * ni + b2p[c + 1];
    o0.z = acc[2] * ni + b2p[c + 2];
    o0.w = acc[3] * ni + b2p[c + 3];
    o1.x = acc[4] * ni + b2p[c + 4];
    o1.y = acc[5] * ni + b2p[c + 5];
    o1.z = acc[6] * ni + b2p[c + 6];
    o1.w = acc[7] * ni + b2p[c + 7];
    float* op = out + (long long)node * 40 + c;
    *(float4*)(op)     = o0;
    *(float4*)(op + 4) = o1;
}

extern "C" void kernel_launch(void* const* d_in, const int* in_sizes, int n_in,
                              void* d_out, int out_size, void* d_ws, size_t ws_size,
                              hipStream_t stream) {
    const float* x   = (const float*)d_in[0];
    const int*   ei  = (const int*)  d_in[1];
    const float* W1  = (const float*)d_in[2];
    const float* b1  = (const float*)d_in[3];
    const float* W2  = (const float*)d_in[4];
    const float* b2  = (const float*)d_in[5];
    const float* Wfc = (const float*)d_in[6];
    const float* bfc = (const float*)d_in[7];
    float* out = (float*)d_out;

    const int N = in_sizes[0] / 128;
    const int E = in_sizes[1] / 2;
    const int* src = ei;
    const int* dst = ei + E;

    const int nbuck = (N + 511) >> 9;                  // 196 coarse buckets
    const int gemmg = (N + 127) >> 7;                  // 782 gemm blocks
    const int B1 = (E + CHUNK - 1) / CHUNK;            // 391 scatter blocks

    char* p = (char*)d_ws;
    float* norm_out = (float*)p; p += (size_t)N * 4;
    float* norm_in  = (float*)p; p += (size_t)N * 4;
    float* bufA     = (float*)p; p += (size_t)N * 128 * 4;   // h1pre fp16
    float* bufB     = (float*)p; p += (size_t)N * 128 * 4;   // slabs, then G fp16
    int*   deg_in   = (int*)p;   p += (size_t)N * 4;
    int*   row_ptr  = (int*)p;   p += (size_t)N * 4;
    int*   csr_src  = (int*)p;   p += (size_t)NBC * SLAB * 4;   // slab-indexed CSR
    int*   cur_d    = (int*)p;   p += (size_t)1024 * 4;
    int*   cur_s    = (int*)p;   p += (size_t)1024 * 4;
    float* b2p      = (float*)p; p += (size_t)64 * 4;
    unsigned short* Wh1 = (unsigned short*)p; p += (size_t)16384 * 2;
    unsigned short* Wl1 = (unsigned short*)p; p += (size_t)16384 * 2;
    unsigned short* Wh2 = (unsigned short*)p; p += (size_t)6144 * 2;
    unsigned short* Wl2 = (unsigned short*)p; p += (size_t)6144 * 2;

    // partition slabs alias bufB (consumed by fine before gather writes G)
    unsigned int*   ppack  = (unsigned int*)bufB;
    unsigned short* es_loc = (unsigned short*)(ppack + (size_t)NBC * SLAB);

    __half* h1pre = (__half*)bufA;   // N x 128 fp16 (UNSCALED X@W1)
    __half* G     = (__half*)bufB;   // N x 64 fp16 PADDED (fused-gather output)

    const int T = 256;

    // setup: cursors + W1/W2p frag conversion + b2p
    setup_kernel<<<(16384 + 6144 + 40 + T - 1) / T, T, 0, stream>>>(
        W1, W2, Wfc, b2, bfc, Wh1, Wl1, Wh2, Wl2, b2p, cur_d, cur_s, nbuck);
    // partition (1024-thread blocks, 196 coarse buckets, int4 register edges)
    scatter_res_kernel<<<B1, 1024, 0, stream>>>(src, dst, cur_d, cur_s,
                                                ppack, es_loc, E);
    // CO-LAUNCH: fine (512-node buckets, blocks [0,196)) || gemm (rest)
    fine_gemm_kernel<<<nbuck + gemmg, T, 0, stream>>>(
        ppack, cur_d, es_loc, cur_s, deg_in, norm_in, row_ptr, csr_src,
        norm_out, N, nbuck, x, Wh1, Wl1, h1pre);
    // fused weighted gather: sum no[s]*Y[s] -> relu -> (h1*no)@W2p -> G
    const int gather_grid = (N + 15) / 16;
    gather_kernel<<<gather_grid, T, 0, stream>>>(h1pre, row_ptr, deg_in, csr_src,
                                                 norm_in, b1, norm_out,
                                                 Wh2, Wl2, G, N);
    // final gather + bias: out = gather(G) * ni + b2p
    gather40_kernel<<<((size_t)N * 5 + T - 1) / T, T, 0, stream>>>(
        G, row_ptr, deg_in, csr_src, norm_in, b2p, out, N);
}

// Round 16
// 259.056 us; speedup vs baseline: 1.1965x; 1.0226x over previous
//
#include <hip/hip_runtime.h>
#include <hip/hip_fp16.h>

// ---------------------------------------------------------------------------
// GCN: 2x GraphConv (norm='both') + FC.  fp32 math, fp16 intermediates.
// R2..R8: 5943 -> 325 us (CSR gather, fold FC, MFMA GEMMs, fp16, no atomics).
// R9-R11: reservation partition, lane tuning. 323 us.
// R12/R13: XCD-affinity sliced gather REGRESSED: per-XCD L2 replication of
//      shared tables is structural (gather FETCH == 8 XCDs x compulsory;
//      rate ~3.1-3.6 TB/s == miss-concurrency cap). Gather is at its floor.
// R14-R19: G-row pad, W-frag preconversion (GEMMs LDS-free), gemm40 fused
//      into gather epilogue (h1 never hits HBM), bf16-presplit LDS. 277.5.
// R20/R24: random global atomics REGRESSED BOTH TIMES (cross-XCD coherence
//      serializes device-scope RMWs). RULE: LDS-binned histograms only.
// R21: 1024-thread scatter. 275.1.
// R22: scatter||gemm co-launch NEUTRAL (gemm starves latency-bound scatter).
// R23: fine||gemm co-launch WIN (latency-robust partner). 271.0.
// R25: int4 register-held scatter edges NEUTRAL -> scatter LDS-atomic-bound.
// R26: coarse 512-node scatter buckets (4x longer slab runs) + R14 fine form
//      absorbed into the gemm co-launch. 264.9.
// R27: merge setup into the scatter launch (mega_kernel): blocks [0,23) do
//      W-frag conversion, blocks [23,414) scatter with ZERO-BASED cursors
//      (R24-validated memsetAsync + relative slab offsets). fine reads
//      cur_* as counts. -1 launch, setup hides under scatter.
// ---------------------------------------------------------------------------

#define CHUNK    4096   // edges per scatter block (391 blocks)
#define NBC      256    // coarse bin array (>= nbuck=196)
#define SLAB     9216   // per-bucket slab capacity (mean 8163 + ~11 sigma)
#define NSETUP   23     // setup blocks in mega_kernel (23*1024 >= 22568)

typedef __attribute__((ext_vector_type(8))) short bf16x8;
typedef __attribute__((ext_vector_type(4))) float f32x4;

struct __align__(8)  half4 { __half x, y, z, w; };
struct __align__(16) half8 { __half h[8]; };

__device__ __forceinline__ unsigned short f2bf(float f) {
    union { float f; unsigned u; } v; v.f = f;
    unsigned r = v.u + 0x7FFFu + ((v.u >> 16) & 1u);   // RNE
    return (unsigned short)(r >> 16);
}
__device__ __forceinline__ float bf2f(unsigned short h) {
    union { unsigned u; float f; } v; v.u = ((unsigned)h) << 16;
    return v.f;
}

// ---------------------------------------------------------------------------
// MEGA co-launch: setup (blocks [0,NSETUP)) || scatter (blocks [NSETUP,..)).
// Setup: W1 -> frag-ordered bf16-split; W2p = W2@Wfc folded+converted;
//        b2p = b2@Wfc + bfc.  (independent of scatter)
// Scatter: coarse 512-node buckets, per-bucket slab reservation with
//        ZERO-BASED cursors (memsetAsync'd); int4 register-held edges.
// ---------------------------------------------------------------------------
__global__ __launch_bounds__(1024) void mega_kernel(
        const float* __restrict__ W1, const float* __restrict__ W2,
        const float* __restrict__ Wfc,
        const float* __restrict__ b2, const float* __restrict__ bfc,
        unsigned short* __restrict__ Wh1, unsigned short* __restrict__ Wl1,
        unsigned short* __restrict__ Wh2, unsigned short* __restrict__ Wl2,
        float* __restrict__ b2p,
        const int* __restrict__ src, const int* __restrict__ dst,
        int* __restrict__ cur_d, int* __restrict__ cur_s,
        unsigned int* __restrict__ ppack, unsigned short* __restrict__ es_loc,
        int E) {
    const int tid = threadIdx.x;

    if (blockIdx.x < NSETUP) {
        // ---------------- setup path ----------------
        int idx = blockIdx.x * 1024 + tid;
        if (idx < 16384) {
            // W1[k][nn] -> frag pos for gemm128
            int k = idx >> 7, nn = idx & 127;
            float v = W1[idx];
            int q = k >> 5, j = k & 7, lb = ((k >> 3) & 3) * 16;
            int tcol = nn >> 4;
            int l = lb + (nn & 15);
            int pos = ((tcol * 4 + q) * 64 + l) * 8 + j;
            unsigned short h = f2bf(v);
            Wh1[pos] = h;
            Wl1[pos] = f2bf(v - bf2f(h));
        } else if (idx < 16384 + 6144) {
            // W2p[k][nn] = dot(W2 row k, Wfc col nn) -> frag pos for gemm40
            int i2 = idx - 16384;
            int k = i2 / 48, nn = i2 - k * 48;
            float v = 0.f;
            if (nn < 40) {
                const float* w2row = W2 + k * 128;
                #pragma unroll 8
                for (int jj = 0; jj < 128; ++jj) v += w2row[jj] * Wfc[jj * 40 + nn];
            }
            int t = nn >> 4, q = k >> 5, j = k & 7;
            int l = ((k >> 3) & 3) * 16 + (nn & 15);
            int pos = ((t * 4 + q) * 64 + l) * 8 + j;
            unsigned short h = f2bf(v);
            Wh2[pos] = h;
            Wl2[pos] = f2bf(v - bf2f(h));
        } else if (idx < 16384 + 6144 + 40) {
            int c = idx - (16384 + 6144);
            float a = bfc[c];
            #pragma unroll 8
            for (int j = 0; j < 128; ++j) a += b2[j] * Wfc[j * 40 + c];
            b2p[c] = a;
        }
        return;
    }

    // ---------------- scatter path (R26 form, zero-based cursors) ----------
    __shared__ int hd[NBC], hs[NBC], bd[NBC], bs[NBC];
    if (tid < NBC) { hd[tid] = 0; hs[tid] = 0; }
    __syncthreads();

    const int base = (blockIdx.x - NSETUP) * CHUNK;
    const int rem  = min(CHUNK, E - base);     // edges in this chunk
    const int off  = tid * 4;
    int cnt = 0;
    int s0 = 0, s1 = 0, s2 = 0, s3 = 0;
    int d0 = 0, d1 = 0, d2 = 0, d3 = 0;
    if (off < rem) {
        cnt = min(4, rem - off);
        const int e0 = base + off;
        if (cnt == 4) {
            int4 sv = *(const int4*)(src + e0);
            int4 dv = *(const int4*)(dst + e0);
            s0 = sv.x; s1 = sv.y; s2 = sv.z; s3 = sv.w;
            d0 = dv.x; d1 = dv.y; d2 = dv.z; d3 = dv.w;
        } else {
            s0 = src[e0]; d0 = dst[e0];
            if (cnt > 1) { s1 = src[e0 + 1]; d1 = dst[e0 + 1]; }
            if (cnt > 2) { s2 = src[e0 + 2]; d2 = dst[e0 + 2]; }
        }
        atomicAdd(&hd[((unsigned)d0) >> 9], 1);
        atomicAdd(&hs[((unsigned)s0) >> 9], 1);
        if (cnt > 1) { atomicAdd(&hd[((unsigned)d1) >> 9], 1);
                       atomicAdd(&hs[((unsigned)s1) >> 9], 1); }
        if (cnt > 2) { atomicAdd(&hd[((unsigned)d2) >> 9], 1);
                       atomicAdd(&hs[((unsigned)s2) >> 9], 1); }
        if (cnt > 3) { atomicAdd(&hd[((unsigned)d3) >> 9], 1);
                       atomicAdd(&hs[((unsigned)s3) >> 9], 1); }
    }
    __syncthreads();
    if (tid < NBC) {
        int cd = hd[tid];
        bd[tid] = cd ? (tid * SLAB + atomicAdd(&cur_d[tid], cd)) : 0;
        hd[tid] = 0;
        int cs = hs[tid];
        bs[tid] = cs ? (tid * SLAB + atomicAdd(&cur_s[tid], cs)) : 0;
        hs[tid] = 0;
    }
    __syncthreads();
    if (cnt > 0) {
        #pragma unroll
        for (int k = 0; k < 4; ++k) {
            if (k >= cnt) break;
            int s = (k == 0) ? s0 : (k == 1) ? s1 : (k == 2) ? s2 : s3;
            int d = (k == 0) ? d0 : (k == 1) ? d1 : (k == 2) ? d2 : d3;
            unsigned bin_d = ((unsigned)d) >> 9;
            int pos = bd[bin_d] + atomicAdd(&hd[bin_d], 1);
            ppack[pos] = (((unsigned)d & 511u) << 17) | (unsigned)s;
            unsigned bin_s = ((unsigned)s) >> 9;
            int ps = bs[bin_s] + atomicAdd(&hs[bin_s], 1);
            es_loc[ps] = (unsigned short)(s & 511);
        }
    }
}

// ---------------------------------------------------------------------------
// CO-LAUNCH: fine (blocks [0,nfine), 512-node form) || unscaled gemm128
// (blocks [nfine, nfine+gemmgrid)). cur_d/cur_s hold COUNTS (zero-based).
// ---------------------------------------------------------------------------
__global__ __launch_bounds__(256, 3) void fine_gemm_kernel(
        const unsigned int* __restrict__ ppack, const int* __restrict__ cur_d,
        const unsigned short* __restrict__ es_loc, const int* __restrict__ cur_s,
        int* __restrict__ deg_in, float* __restrict__ norm_in,
        int* __restrict__ row_ptr, int* __restrict__ csr_src,
        float* __restrict__ norm_out, int N_, int nfine,
        const float* __restrict__ X,
        const unsigned short* __restrict__ Wh, const unsigned short* __restrict__ Wl,
        __half* __restrict__ Y) {
    const int tid = threadIdx.x;

    if (blockIdx.x < nfine) {
        // ---------------- fine path (512-node bucket b) ----------
        __shared__ int h[512];
        __shared__ int psum[256];
        const int b = blockIdx.x;
        const int start = b * SLAB;
        const int node0 = b << 9;

        // dst: histogram -> prefix -> CSR scatter
        const int end_d = start + cur_d[b];        // count-based
        h[tid] = 0; h[tid + 256] = 0;
        __syncthreads();
        for (int i = start + tid; i < end_d; i += 256)
            atomicAdd(&h[ppack[i] >> 17], 1);
        __syncthreads();

        int a0 = h[2 * tid], a1 = h[2 * tid + 1];
        int pair = a0 + a1;
        psum[tid] = pair;
        __syncthreads();
        for (int off = 1; off < 256; off <<= 1) {
            int t = (tid >= off) ? psum[tid - off] : 0;
            __syncthreads();
            psum[tid] += t;
            __syncthreads();
        }
        int base0 = psum[tid] - pair + start;   // slab-local CSR position

        int n0 = node0 + 2 * tid, n1 = n0 + 1;
        if (n0 < N_) {
            deg_in[n0]  = a0;
            row_ptr[n0] = base0;
            norm_in[n0] = rsqrtf((float)(a0 < 1 ? 1 : a0));
        }
        if (n1 < N_) {
            deg_in[n1]  = a1;
            row_ptr[n1] = base0 + a0;
            norm_in[n1] = rsqrtf((float)(a1 < 1 ? 1 : a1));
        }
        h[2 * tid]     = base0;
        h[2 * tid + 1] = base0 + a0;
        __syncthreads();

        for (int i = start + tid; i < end_d; i += 256) {
            unsigned int pk = ppack[i];
            int pos = atomicAdd(&h[pk >> 17], 1);
            csr_src[pos] = (int)(pk & 0x1FFFFu);
        }
        __syncthreads();

        // src: histogram -> norm_out
        const int end_s = start + cur_s[b];        // count-based
        h[tid] = 0; h[tid + 256] = 0;
        __syncthreads();
        for (int i = start + tid; i < end_s; i += 256)
            atomicAdd(&h[(int)es_loc[i]], 1);
        __syncthreads();

        int m0 = node0 + tid, m1 = m0 + 256;
        if (m0 < N_) { int d = h[tid];       norm_out[m0] = rsqrtf((float)(d < 1 ? 1 : d)); }
        if (m1 < N_) { int d = h[tid + 256]; norm_out[m1] = rsqrtf((float)(d < 1 ? 1 : d)); }
        return;
    }

    // ---------------- gemm path (unscaled Y = X @ W1) ----------------
    const int blk  = blockIdx.x - nfine;
    const int lane = tid & 63;
    const int w    = tid >> 6;
    const int m    = lane & 15;
    const int quad = lane >> 4;
    const int rowBase = blk * 128 + w * 32;
    const int nrows = N_;

    bf16x8 Ah[2][4], Al[2][4];
    #pragma unroll
    for (int rt = 0; rt < 2; ++rt) {
        int r = rowBase + rt * 16 + m;
        const float* xr = X + (size_t)(r < nrows ? r : 0) * 128;
        const float z = (r < nrows) ? 1.f : 0.f;
        #pragma unroll
        for (int q = 0; q < 4; ++q) {
            int k0 = q * 32 + quad * 8;
            float4 a = *(const float4*)(xr + k0);
            float4 bv = *(const float4*)(xr + k0 + 4);
            float v[8] = {a.x * z, a.y * z, a.z * z, a.w * z,
                          bv.x * z, bv.y * z, bv.z * z, bv.w * z};
            bf16x8 hi, lo;
            #pragma unroll
            for (int j = 0; j < 8; ++j) {
                unsigned short h = f2bf(v[j]);
                hi[j] = (short)h;
                lo[j] = (short)f2bf(v[j] - bf2f(h));
            }
            Ah[rt][q] = hi; Al[rt][q] = lo;
        }
    }

    f32x4 acc[2][8];
    #pragma unroll
    for (int rt = 0; rt < 2; ++rt)
        #pragma unroll
        for (int t = 0; t < 8; ++t)
            acc[rt][t] = (f32x4){0.f, 0.f, 0.f, 0.f};

    #pragma unroll
    for (int t = 0; t < 8; ++t) {
        #pragma unroll
        for (int q = 0; q < 4; ++q) {
            const int off = ((t * 4 + q) * 64 + lane) * 8;
            bf16x8 Bh = *(const bf16x8*)(Wh + off);
            bf16x8 Bl = *(const bf16x8*)(Wl + off);
            #pragma unroll
            for (int rt = 0; rt < 2; ++rt) {
                acc[rt][t] = __builtin_amdgcn_mfma_f32_16x16x32_bf16(Ah[rt][q], Bh, acc[rt][t], 0, 0, 0);
                acc[rt][t] = __builtin_amdgcn_mfma_f32_16x16x32_bf16(Ah[rt][q], Bl, acc[rt][t], 0, 0, 0);
                acc[rt][t] = __builtin_amdgcn_mfma_f32_16x16x32_bf16(Al[rt][q], Bh, acc[rt][t], 0, 0, 0);
            }
        }
    }

    #pragma unroll
    for (int rt = 0; rt < 2; ++rt) {
        int r0 = rowBase + rt * 16 + quad * 4;
        #pragma unroll
        for (int reg = 0; reg < 4; ++reg) {
            int r = r0 + reg;
            if (r >= nrows) continue;
            __half* yr = Y + (size_t)r * 128 + m;
            #pragma unroll
            for (int t = 0; t < 8; ++t)
                yr[t * 16] = __float2half(acc[rt][t][reg]);
        }
    }
}

// ---------------------------------------------------------------------------
// FUSED WEIGHTED gather + layer-1 GEMM.
// Phase 1 (all 256 threads): h1[node] = relu((sum_s no[s]*Y[s]) * ni + b1)
//   (Y is UNSCALED X@W1; norm_out applied per-edge, table L2-hot), then
//   pre-scaled by norm_out[node] and SPLIT to bf16 hi/lo in LDS.
// Phase 2 (waves 0-2): pure ds_read_b128 A-frags + 12 MFMA -> G[16 x 40].
// h1 never touches global memory.
// ---------------------------------------------------------------------------
__global__ __launch_bounds__(256, 4) void gather_kernel(
        const __half* __restrict__ H, const int* __restrict__ row_ptr,
        const int* __restrict__ deg, const int* __restrict__ csr_src,
        const float* __restrict__ norm_in, const float* __restrict__ b,
        const float* __restrict__ norm_out,
        const unsigned short* __restrict__ Wh2, const unsigned short* __restrict__ Wl2,
        __half* __restrict__ G, int n) {
    __shared__ unsigned short h1h[16][136];   // bf16 hi, stride 136 (2-way alias max)
    __shared__ unsigned short h1l[16][136];   // bf16 lo
    const int tid   = threadIdx.x;
    const int node0 = blockIdx.x * 16;
    const int g     = tid >> 4;              // node-in-block 0..15
    const int node  = node0 + g;
    const int c     = (tid & 15) * 8;        // column group
    const bool active = node < n;

    int start = 0, cnt = 0;
    if (active) { start = row_ptr[node]; cnt = deg[node]; }
    float acc[8] = {0.f, 0.f, 0.f, 0.f, 0.f, 0.f, 0.f, 0.f};

    int j = 0;
    for (; j + 4 <= cnt; j += 4) {
        int s0 = csr_src[start + j];
        int s1 = csr_src[start + j + 1];
        int s2 = csr_src[start + j + 2];
        int s3 = csr_src[start + j + 3];
        float n0 = norm_out[s0], n1 = norm_out[s1];
        float n2 = norm_out[s2], n3 = norm_out[s3];
        half8 v0 = *(const half8*)(H + (long long)s0 * 128 + c);
        half8 v1 = *(const half8*)(H + (long long)s1 * 128 + c);
        half8 v2 = *(const half8*)(H + (long long)s2 * 128 + c);
        half8 v3 = *(const half8*)(H + (long long)s3 * 128 + c);
        #pragma unroll
        for (int k = 0; k < 8; ++k) {
            float t0 = fmaf(n0, __half2float(v0.h[k]), fmaf(n1, __half2float(v1.h[k]), acc[k]));
            acc[k] = fmaf(n2, __half2float(v2.h[k]), fmaf(n3, __half2float(v3.h[k]), t0));
        }
    }
    for (; j < cnt; ++j) {
        int s0 = csr_src[start + j];
        float n0 = norm_out[s0];
        half8 v0 = *(const half8*)(H + (long long)s0 * 128 + c);
        #pragma unroll
        for (int k = 0; k < 8; ++k) acc[k] = fmaf(n0, __half2float(v0.h[k]), acc[k]);
    }

    float ni = active ? norm_in[node]  : 0.f;
    float no = active ? norm_out[node] : 0.f;   // layer-1 row scale, pre-applied
    float4 b0  = *(const float4*)(b + c);
    float4 b1v = *(const float4*)(b + c + 4);
    float bb[8] = {b0.x, b0.y, b0.z, b0.w, b1v.x, b1v.y, b1v.z, b1v.w};
    bf16x8 hi, lo;
    #pragma unroll
    for (int k = 0; k < 8; ++k) {
        float hv = fmaxf(acc[k] * ni + bb[k], 0.f) * no;
        unsigned short h = f2bf(hv);
        hi[k] = (short)h;
        lo[k] = (short)f2bf(hv - bf2f(h));
    }
    *(bf16x8*)&h1h[g][c] = hi;
    *(bf16x8*)&h1l[g][c] = lo;
    __syncthreads();

    // phase 2: waves 0..2 each compute one 16-col tile of G (pure LDS+MFMA)
    const int w = tid >> 6;
    if (w < 3) {
        const int lane = tid & 63;
        const int m    = lane & 15;
        const int quad = lane >> 4;

        f32x4 a3 = (f32x4){0.f, 0.f, 0.f, 0.f};
        const int t = w;
        #pragma unroll
        for (int q = 0; q < 4; ++q) {
            const int k0 = q * 32 + quad * 8;
            bf16x8 Ah = *(const bf16x8*)&h1h[m][k0];
            bf16x8 Al = *(const bf16x8*)&h1l[m][k0];
            const int off = ((t * 4 + q) * 64 + lane) * 8;
            bf16x8 Bh = *(const bf16x8*)(Wh2 + off);
            bf16x8 Bl = *(const bf16x8*)(Wl2 + off);
            a3 = __builtin_amdgcn_mfma_f32_16x16x32_bf16(Ah, Bh, a3, 0, 0, 0);
            a3 = __builtin_amdgcn_mfma_f32_16x16x32_bf16(Ah, Bl, a3, 0, 0, 0);
            a3 = __builtin_amdgcn_mfma_f32_16x16x32_bf16(Al, Bh, a3, 0, 0, 0);
        }

        const int col = t * 16 + m;
        if (col < 40) {
            const int r0 = node0 + quad * 4;
            #pragma unroll
            for (int reg = 0; reg < 4; ++reg) {
                int r = r0 + reg;
                if (r < n) G[(size_t)r * 64 + col] = __float2half(a3[reg]);
            }
        }
    }
}

// 40-dim gather (fp16 in, PADDED stride 64; fp32 out): out = (sum G[src])*ni + b2p
// 5 lanes per node, one half8 (16 B) each.
__global__ __launch_bounds__(256) void gather40_kernel(
        const __half* __restrict__ G, const int* __restrict__ row_ptr,
        const int* __restrict__ deg, const int* __restrict__ csr_src,
        const float* __restrict__ norm_in, const float* __restrict__ b2p,
        float* __restrict__ out, int n) {
    const int t = blockIdx.x * 256 + threadIdx.x;
    if (t >= n * 5) return;
    const int node = t / 5;
    const int c    = (t - node * 5) * 8;

    const int start = row_ptr[node];
    const int cnt   = deg[node];
    float acc[8] = {0.f, 0.f, 0.f, 0.f, 0.f, 0.f, 0.f, 0.f};

    int j = 0;
    for (; j + 4 <= cnt; j += 4) {
        int s0 = csr_src[start + j];
        int s1 = csr_src[start + j + 1];
        int s2 = csr_src[start + j + 2];
        int s3 = csr_src[start + j + 3];
        half8 v0 = *(const half8*)(G + (long long)s0 * 64 + c);
        half8 v1 = *(const half8*)(G + (long long)s1 * 64 + c);
        half8 v2 = *(const half8*)(G + (long long)s2 * 64 + c);
        half8 v3 = *(const half8*)(G + (long long)s3 * 64 + c);
        #pragma unroll
        for (int k = 0; k < 8; ++k)
            acc[k] += (__half2float(v0.h[k]) + __half2float(v1.h[k]))
                    + (__half2float(v2.h[k]) + __half2float(v3.h[k]));
    }
    for (; j < cnt; ++j) {
        int s0 = csr_src[start + j];
        half8 v0 = *(const half8*)(G + (long long)s0 * 64 + c);
        #pragma unroll
        for (int k = 0; k < 8; ++k) acc[k] += __half2float(v0.h[k]);
    }

    float ni = norm_in[node];
    float4 o0, o1;
    o0.x = acc[0] * ni + b2p[c + 0];
    o0.y = acc[1] * ni + b2p[c + 1];
    o0.z = acc[2] * ni + b2p[c + 2];
    o0.w = acc[3] * ni + b2p[c + 3];
    o1.x = acc[4] * ni + b2p[c + 4];
    o1.y = acc[5] * ni + b2p[c + 5];
    o1.z = acc[6] * ni + b2p[c + 6];
    o1.w = acc[7] * ni + b2p[c + 7];
    float* op = out + (long long)node * 40 + c;
    *(float4*)(op)     = o0;
    *(float4*)(op + 4) = o1;
}

extern "C" void kernel_launch(void* const* d_in, const int* in_sizes, int n_in,
                              void* d_out, int out_size, void* d_ws, size_t ws_size,
                              hipStream_t stream) {
    const float* x   = (const float*)d_in[0];
    const int*   ei  = (const int*)  d_in[1];
    const float* W1  = (const float*)d_in[2];
    const float* b1  = (const float*)d_in[3];
    const float* W2  = (const float*)d_in[4];
    const float* b2  = (const float*)d_in[5];
    const float* Wfc = (const float*)d_in[6];
    const float* bfc = (const float*)d_in[7];
    float* out = (float*)d_out;

    const int N = in_sizes[0] / 128;
    const int E = in_sizes[1] / 2;
    const int* src = ei;
    const int* dst = ei + E;

    const int nbuck = (N + 511) >> 9;                  // 196 coarse buckets
    const int gemmg = (N + 127) >> 7;                  // 782 gemm blocks
    const int B1 = (E + CHUNK - 1) / CHUNK;            // 391 scatter blocks

    char* p = (char*)d_ws;
    float* norm_out = (float*)p; p += (size_t)N * 4;
    float* norm_in  = (float*)p; p += (size_t)N * 4;
    float* bufA     = (float*)p; p += (size_t)N * 128 * 4;   // h1pre fp16
    float* bufB     = (float*)p; p += (size_t)N * 128 * 4;   // slabs, then G fp16
    int*   deg_in   = (int*)p;   p += (size_t)N * 4;
    int*   row_ptr  = (int*)p;   p += (size_t)N * 4;
    int*   csr_src  = (int*)p;   p += (size_t)NBC * SLAB * 4;   // slab-indexed CSR
    int*   cur_d    = (int*)p;   p += (size_t)1024 * 4;      // zero-based counts
    int*   cur_s    = (int*)p;   p += (size_t)1024 * 4;
    float* b2p      = (float*)p; p += (size_t)64 * 4;
    unsigned short* Wh1 = (unsigned short*)p; p += (size_t)16384 * 2;
    unsigned short* Wl1 = (unsigned short*)p; p += (size_t)16384 * 2;
    unsigned short* Wh2 = (unsigned short*)p; p += (size_t)6144 * 2;
    unsigned short* Wl2 = (unsigned short*)p; p += (size_t)6144 * 2;

    // partition slabs alias bufB (consumed by fine before gather writes G)
    unsigned int*   ppack  = (unsigned int*)bufB;
    unsigned short* es_loc = (unsigned short*)(ppack + (size_t)NBC * SLAB);

    __half* h1pre = (__half*)bufA;   // N x 128 fp16 (UNSCALED X@W1)
    __half* G     = (__half*)bufB;   // N x 64 fp16 PADDED (fused-gather output)

    const int T = 256;

    // zero slab cursors (contiguous cur_d|cur_s), then MEGA co-launch:
    // setup (23 blocks) || scatter (391 blocks), both 1024 threads.
    hipMemsetAsync(cur_d, 0, (size_t)2048 * 4, stream);
    mega_kernel<<<NSETUP + B1, 1024, 0, stream>>>(
        W1, W2, Wfc, b2, bfc, Wh1, Wl1, Wh2, Wl2, b2p,
        src, dst, cur_d, cur_s, ppack, es_loc, E);
    // CO-LAUNCH: fine (512-node buckets, blocks [0,196)) || gemm (rest)
    fine_gemm_kernel<<<nbuck + gemmg, T, 0, stream>>>(
        ppack, cur_d, es_loc, cur_s, deg_in, norm_in, row_ptr, csr_src,
        norm_out, N, nbuck, x, Wh1, Wl1, h1pre);
    // fused weighted gather: sum no[s]*Y[s] -> relu -> (h1*no)@W2p -> G
    const int gather_grid = (N + 15) / 16;
    gather_kernel<<<gather_grid, T, 0, stream>>>(h1pre, row_ptr, deg_in, csr_src,
                                                 norm_in, b1, norm_out,
                                                 Wh2, Wl2, G, N);
    // final gather + bias: out = gather(G) * ni + b2p
    gather40_kernel<<<((size_t)N * 5 + T - 1) / T, T, 0, stream>>>(
        G, row_ptr, deg_in, csr_src, norm_in, b2p, out, N);
}